// Round 5
// baseline (6345.266 us; speedup 1.0000x reference)
//
#include <hip/hip_runtime.h>

// LabelPropagator — low-footprint pipeline (6.27 MB ws).
// Inputs runtime-dtype-detected (f32 vs bf16); OUTPUT = FLOAT32 (ref out dtype).
// Shapes: S=4, c=512, kd=128, P=h*w=1024, F=16 (16384 cross keys), ce=16.
//
// R3: VALU LDS-tiled crossfuse: 2.88 ms, latency-bound (VALUBusy 32%, Occ 12%).
// R4: (512,4) bound -> VGPR 64 -> kr[16] spilled -> 9 GB scratch FETCH. Dead end:
//     K-row-in-regs needs >=128 VGPR, occupancy wants <=128. VALU loses.
// R5: phase B -> MFMA (scores 17.2 GF + PV 2.1 GF are bf16 matmuls; matrix pipe
//     does this in ~10 us). Kl bf16 [key][d] XOR-swizzled (byte^=(key&7)<<4),
//     PE bf16 [e][k] swizzled + B-frags hoisted to regs; P staged per-wave in
//     4KB swizzled LDS tile (C-layout write, A-layout b128 read). Z via
//     shfl_xor butterfly. Phase A (f32 projection) unchanged from R3.

typedef __attribute__((ext_vector_type(8))) short short8v;
typedef __attribute__((ext_vector_type(4))) float float4v;
typedef __attribute__((ext_vector_type(4))) unsigned int uint4v;

__device__ __forceinline__ float b2f(unsigned short h){
  union { unsigned int u; float f; } c; c.u = ((unsigned int)h) << 16; return c.f;
}
__device__ __forceinline__ unsigned short f2b(float f){
  union { float f; unsigned int u; } c; c.f = f;
  unsigned int u = c.u;
  u += 0x7fffu + ((u >> 16) & 1u);     // round-to-nearest-even
  return (unsigned short)(u >> 16);
}
// flag resolve: fi==-1 forced f32, fi==-2 forced bf16, else flags[fi] (1=f32,0=bf16)
__device__ __forceinline__ int getf(const int* flags, int fi){
  return (fi == -1) ? 1 : ((fi == -2) ? 0 : flags[fi]);
}
__device__ __forceinline__ float ld1(const void* p, long i, int f32f){
  return f32f ? ((const float*)p)[i] : b2f(((const unsigned short*)p)[i]);
}
__device__ __forceinline__ void ld8(const void* p, long i, int f32f, float* o){
  if (f32f){
    float4v a = *(const float4v*)((const float*)p + i);
    float4v b = *(const float4v*)((const float*)p + i + 4);
    o[0]=a[0];o[1]=a[1];o[2]=a[2];o[3]=a[3];o[4]=b[0];o[5]=b[1];o[6]=b[2];o[7]=b[3];
  } else {
    short8v v = *(const short8v*)((const unsigned short*)p + i);
    #pragma unroll
    for (int j=0;j<8;j++) o[j] = b2f((unsigned short)v[j]);
  }
}

__device__ __forceinline__ float4v mfma16(short8v a, short8v b, float4v c){
  return __builtin_amdgcn_mfma_f32_16x16x32_bf16(a, b, c, 0, 0, 0);
}

// ---------------------------------------------------------------------------
// k_detect: flags[i]=1 if input i is f32 (bf16-exponent>=200 rate > 6.25% over
// first min(n,8192) uint16s; f32-as-bf16 gives ~11%, real bf16 data ~0%).
// ---------------------------------------------------------------------------
__global__ __launch_bounds__(256) void k_detect(
    const void* p0, const void* p1, const void* p2, const void* p3,
    const void* p4, const void* p5, const void* p6,
    int n0, int n1, int n2, int n3, int n4, int n5, int n6,
    int* __restrict__ flags)
{
  const int i = blockIdx.x, t = threadIdx.x;
  const void* ps[7] = {p0,p1,p2,p3,p4,p5,p6};
  int ns[7] = {n0,n1,n2,n3,n4,n5,n6};
  const unsigned short* u = (const unsigned short*)ps[i];
  int n = ns[i]; if (n > 8192) n = 8192;
  int cnt = 0;
  for (int k=t; k<n; k+=256){
    int e = (u[k] >> 7) & 0xFF;
    cnt += (e >= 200) ? 1 : 0;
  }
  __shared__ int red[256];
  red[t] = cnt; __syncthreads();
  for (int off=128; off>0; off>>=1){
    if (t < off) red[t] += red[t+off];
    __syncthreads();
  }
  if (t == 0) flags[i] = (red[0]*16 > n) ? 1 : 0;
}

// ---------------------------------------------------------------------------
// k_proj_g: Out[s][n][128] (bf16) = l2norm(X_token(n) @ W^T + b)
// X layout: [(f*4+s)*512 + ch]*1024 + p, f=n>>10, p=n&1023. Block=128 (d).
// ---------------------------------------------------------------------------
__global__ __launch_bounds__(128) void k_proj_g(
    const void* __restrict__ Xv, int xfi,
    const void* __restrict__ Wv, int wfi,
    const void* __restrict__ Bv, int bfi,
    const int* __restrict__ flags,
    unsigned short* __restrict__ Out, int Ntot)
{
  const int n = blockIdx.x, s = blockIdx.y, d = threadIdx.x;
  const int xf = getf(flags,xfi), wf = getf(flags,wfi), bf = getf(flags,bfi);
  const int f = n >> 10, p = n & 1023;
  const long base = ((long)(f*4 + s) * 512) * 1024 + p;
  float acc = ld1(Bv, d, bf);
  const long wbase = (long)d * 512;
  float wv[8];
  for (int ch=0; ch<512; ch+=8){
    ld8(Wv, wbase + ch, wf, wv);
    #pragma unroll
    for (int j=0;j<8;j++)
      acc += ld1(Xv, base + (long)(ch+j)*1024, xf) * wv[j];
  }
  __shared__ float red[128];
  red[d] = acc*acc;
  __syncthreads();
  for (int off=64; off>0; off>>=1){
    if (d < off) red[d] += red[d+off];
    __syncthreads();
  }
  float r = 1.f / fmaxf(sqrtf(fmaxf(red[0], 0.f)), 1e-12f);
  Out[((long)s*Ntot + n)*128 + d] = f2b(acc * r);
}

// ---------------------------------------------------------------------------
// k_self: per (s,n): fixed-shift softmax over 1024 keys (exp(30d-30), diag
// key => Z>=~1; identical to ref softmax), PV over 512 ch, residual add.
// Y[s][ch][n] (bf16) = tgt + attn.
// ---------------------------------------------------------------------------
__global__ __launch_bounds__(256) void k_self(
    const unsigned short* __restrict__ wq,   // [s][1024][128] bf16 (ws)
    const void* __restrict__ tgt,            // [s][512][1024] flagged
    const int* __restrict__ flags,
    unsigned short* __restrict__ Y)          // [s][512][1024] bf16
{
  const int n = blockIdx.x, s = blockIdx.y, t = threadIdx.x;
  const int tf = flags[0];
  __shared__ float qrow[128];
  __shared__ float ps[1024];
  __shared__ float zred[256];
  if (t < 128) qrow[t] = b2f(wq[((long)s*1024 + n)*128 + t]);
  __syncthreads();
  float zp = 0.f;
  #pragma unroll
  for (int kb=0; kb<4; kb++){
    int k = t + kb*256;
    const unsigned short* kr = wq + ((long)s*1024 + k)*128;
    float dot = 0.f;
    for (int d2=0; d2<128; d2+=8){
      short8v kv = *(const short8v*)(kr + d2);
      #pragma unroll
      for (int j=0;j<8;j++) dot += qrow[d2+j] * b2f((unsigned short)kv[j]);
    }
    float pv = __expf(30.f*dot - 30.f);
    ps[k] = pv; zp += pv;
  }
  zred[t] = zp; __syncthreads();
  for (int off=128; off>0; off>>=1){
    if (t < off) zred[t] += zred[t+off];
    __syncthreads();
  }
  float iz = 1.f / fmaxf(zred[0], 1e-30f);
  float vv[8];
  #pragma unroll
  for (int cb=0; cb<2; cb++){
    int ch = t + cb*256;
    const long vrbase = ((long)s*512 + ch)*1024;
    float acc = 0.f;
    for (int k=0; k<1024; k+=8){
      ld8(tgt, vrbase + k, tf, vv);
      #pragma unroll
      for (int j=0;j<8;j++) acc += ps[k+j] * vv[j];
    }
    Y[vrbase + n] = f2b(ld1(tgt, vrbase + n, tf) + acc*iz);
  }
}

// ---------------------------------------------------------------------------
// k_inorm: in-place InstanceNorm (biased var, eps 1e-5) over 1024 tokens.
// ---------------------------------------------------------------------------
__global__ __launch_bounds__(256) void k_inorm(unsigned short* __restrict__ Y)
{
  const int ch = blockIdx.x, s = blockIdx.y, t = threadIdx.x;
  unsigned short* row = Y + ((long)s*512 + ch)*1024;
  float v[4]; float sum=0.f, ss=0.f;
  #pragma unroll
  for (int i=0;i<4;i++){ v[i]=b2f(row[t+256*i]); sum+=v[i]; ss+=v[i]*v[i]; }
  __shared__ float r1[256], r2[256];
  r1[t]=sum; r2[t]=ss; __syncthreads();
  for (int off=128; off>0; off>>=1){
    if (t<off){ r1[t]+=r1[t+off]; r2[t]+=r2[t+off]; }
    __syncthreads();
  }
  float mean = r1[0]*(1.f/1024.f);
  float var  = fmaxf(r2[0]*(1.f/1024.f) - mean*mean, 0.f);
  float rstd = rsqrtf(var + 1e-5f);
  #pragma unroll
  for (int i=0;i<4;i++) row[t+256*i] = f2b((v[i]-mean)*rstd);
}

// ---------------------------------------------------------------------------
// k_crossfuse (R5): block = (key-chunk c, s), 256 threads (4 waves).
// Chunk = 128 keys of frame f=c>>3 at p0=(c&7)*128. Partial-group grp=c&7.
//
// Phase A (VALU f32, as R3): thread (kk=t&127, hh=t>>7) projects+l2norms its
//   key's 64 dims; stores bf16 to Kl[key][d] with XOR swizzle
//   byte = key*256 + ((d*2) ^ ((key&7)<<4))   (16B granules).
// Phase A2: PE tile bf16 [e][k], swizzle byte = e*256 + ((k*2) ^ ((e&7)<<4)).
// Phase B (MFMA, per-wave independent, no block barriers):
//   PE B-frags (4) hoisted to regs once. Wave wv handles q-tiles qt=wv,wv+4,..
//   Per q-tile (16 q): Q A-frags (4) from global; for kt=0..7: 4 x
//   mfma_f32_16x16x32_bf16 -> S (C: col=key=l&15, row=q=(l>>4)*4+r);
//   p=exp(30S-30); z[r]+=p; p->bf16 into per-wave swizzled Pl tile (C-layout
//   scatter). Then 4 MFMA P(A-frag) x PE(B-frag) -> O; z butterfly
//   (shfl_xor 1/2/4/8); atomicAdd O (4/lane) + Z into group partial.
// ---------------------------------------------------------------------------
__global__ __launch_bounds__(256, 2) void k_crossfuse(
    const unsigned short* __restrict__ wqC,  // [s][1024][128] bf16 (ws)
    const void* __restrict__ mem,            // [(f*4+s)*512+ch][1024] flagged
    const void* __restrict__ pe,             // [(f*4+s)*16+e][1024] flagged
    const void* __restrict__ Wv,             // [128][512] flagged
    const void* __restrict__ Bv,             // [128] flagged
    const int* __restrict__ flags,
    float* __restrict__ OZp)                 // [8 grp][4 s][1024][17] f32, zeroed
{
  const int c = blockIdx.x, s = blockIdx.y, t = threadIdx.x;
  const int f = c >> 3, p0 = (c & 7) * 128, grp = c & 7;
  const int mf = flags[1], pf = flags[2], wf = flags[5], bf = flags[6];

  __shared__ unsigned short Kl[128*128];   // 32 KB [key][d] bf16 XOR-swizzled
  __shared__ unsigned short PEb[16*128];   //  4 KB [e][k]  bf16 XOR-swizzled
  __shared__ unsigned short Pl[4*16*128];  // 16 KB per-wave [q][k] bf16 swz
  __shared__ float ssred[256];

  // ---- Phase A: project + normalize 128 keys (thread = (key kk, half hh))
  const int kk = t & 127, hh = t >> 7;
  {
    float acc[64];
    #pragma unroll
    for (int d=0; d<64; d++) acc[d] = 0.f;
    const long xcol = ((long)(f*4 + s) * 512) * 1024 + p0 + kk;
    for (int ch=0; ch<512; ch+=8){
      float xv[8];
      #pragma unroll
      for (int j=0;j<8;j++) xv[j] = ld1(mem, xcol + (long)(ch+j)*1024, mf);
      #pragma unroll
      for (int d=0; d<64; d++){
        float wv8[8];
        ld8(Wv, (long)(hh*64 + d)*512 + ch, wf, wv8);
        #pragma unroll
        for (int j=0;j<8;j++) acc[d] += xv[j]*wv8[j];
      }
    }
    float ss = 0.f;
    #pragma unroll
    for (int d=0; d<64; d++){
      acc[d] += ld1(Bv, hh*64 + d, bf);
      ss += acc[d]*acc[d];
    }
    ssred[kk*2 + hh] = ss;
    __syncthreads();
    float inv = 1.f / fmaxf(sqrtf(fmaxf(ssred[kk*2] + ssred[kk*2+1], 0.f)), 1e-12f);
    // swizzled bf16 stores: 8 x b128; granule g (8 dims) at byte
    // kk*256 + ((g*16) ^ ((kk&7)<<4))
    char* krow = (char*)Kl + kk*256;
    const int xk = (kk & 7) << 4;
    #pragma unroll
    for (int gg=0; gg<8; gg++){
      const int g = hh*8 + gg;
      uint4v v;
      #pragma unroll
      for (int w=0; w<4; w++){
        unsigned int lo = f2b(acc[gg*8 + 2*w]   * inv);
        unsigned int hi = f2b(acc[gg*8 + 2*w+1] * inv);
        v[w] = lo | (hi << 16);
      }
      *(uint4v*)(krow + ((g*16) ^ xk)) = v;
    }
  }
  // ---- Phase A2: pos_enc tile bf16 [e][k] swizzled; thread t -> e=t>>4,
  //      k0=(t&15)*8 (one b128 per thread covers 16x128)
  {
    const int e = t >> 4, k0 = (t & 15) * 8;
    float pv8[8];
    ld8(pe, ((long)((f*4 + s)*16 + e))*1024 + p0 + k0, pf, pv8);
    uint4v v;
    #pragma unroll
    for (int w=0; w<4; w++){
      unsigned int lo = f2b(pv8[2*w]);
      unsigned int hi = f2b(pv8[2*w+1]);
      v[w] = lo | (hi << 16);
    }
    *(uint4v*)((char*)PEb + e*256 + (((k0*2)) ^ ((e & 7) << 4))) = v;
  }
  __syncthreads();

  // ---- Phase B: MFMA, waves independent
  const int l = t & 63, wv = t >> 6;
  const int lr = l & 15, lg = l >> 4;      // frag 16-dim index / k-group
  char* PlW = (char*)Pl + wv*4096;         // per-wave P tile

  // PE B-frags: lane l holds PE[k=(lg*8..+7)+kb*32][e=lr]
  short8v peb[4];
  #pragma unroll
  for (int kb=0; kb<4; kb++){
    const int k0 = kb*32 + lg*8;
    peb[kb] = *(const short8v*)((char*)PEb + lr*256 + ((k0*2) ^ ((lr & 7) << 4)));
  }

  for (int qt = wv; qt < 64; qt += 4){
    // Q A-frags: lane l holds Q[q=qt*16+lr][k=kb*32+lg*8 ..+7]
    short8v qf[4];
    const unsigned short* qbase = wqC + ((long)s*1024 + qt*16 + lr)*128;
    #pragma unroll
    for (int kb=0; kb<4; kb++)
      qf[kb] = *(const short8v*)(qbase + kb*32 + lg*8);

    float zacc[4] = {0.f, 0.f, 0.f, 0.f};
    #pragma unroll 1
    for (int kt=0; kt<8; ++kt){
      float4v sacc = {0.f, 0.f, 0.f, 0.f};
      const int key = kt*16 + lr;
      const char* krow = (const char*)Kl + key*256;
      const int xk = (key & 7) << 4;
      #pragma unroll
      for (int kb=0; kb<4; kb++){
        short8v kf = *(const short8v*)(krow + (((kb*32 + lg*8)*2) ^ xk));
        sacc = mfma16(qf[kb], kf, sacc);
      }
      // S -> P (C-layout: col=key=lr, row q=lg*4+r), scatter to Pl
      #pragma unroll
      for (int r=0; r<4; r++){
        float p = __expf(30.f*sacc[r] - 30.f);
        zacc[r] += p;
        const int q = lg*4 + r;
        *(unsigned short*)(PlW + q*256 + (((kt*16 + lr)*2) ^ ((q & 7) << 4))) = f2b(p);
      }
    }
    // PV: P A-frags (lane: row q=lr, k=kb*32+lg*8..+7) x PE B-frags
    float4v pv = {0.f, 0.f, 0.f, 0.f};
    #pragma unroll
    for (int kb=0; kb<4; kb++){
      const int k0 = kb*32 + lg*8;
      short8v pf8 = *(const short8v*)(PlW + lr*256 + ((k0*2) ^ ((lr & 7) << 4)));
      pv = mfma16(pf8, peb[kb], pv);
    }
    // Z: butterfly over the 16 cols (lanes lr=0..15 within group)
    #pragma unroll
    for (int r=0; r<4; r++){
      float z = zacc[r];
      z += __shfl_xor(z, 1);
      z += __shfl_xor(z, 2);
      z += __shfl_xor(z, 4);
      z += __shfl_xor(z, 8);
      zacc[r] = z;
    }
    float* oz = OZp + ((((long)grp*4 + s)*1024) + qt*16)*17;
    #pragma unroll
    for (int r=0; r<4; r++)
      atomicAdd(&oz[(lg*4 + r)*17 + lr], pv[r]);
    if (lr == 0){
      #pragma unroll
      for (int r=0; r<4; r++)
        atomicAdd(&oz[(lg*4 + r)*17 + 16], zacc[r]);
    }
  }
}

// ---------------------------------------------------------------------------
// k_final: out (FLOAT32) = sigmoid(O/Z) summing 8 group partials; diagnostic
// if ws too small. out[i], i = ((s*16+e)<<10)+n.
// ---------------------------------------------------------------------------
__global__ __launch_bounds__(256) void k_final(
    const float* __restrict__ OZp, float* __restrict__ out,
    const int* __restrict__ flags, int sane, int detect_ok, int ws_mb)
{
  const int i = blockIdx.x*256 + threadIdx.x;   // 0..65535
  if (!sane){
    float v = 0.5f;
    if (i == 0){
      int F = 0;
      if (detect_ok)
        F = flags[0]*16 + flags[1]*8 + flags[2]*4 + flags[3]*2 + flags[5];
      int wm = ws_mb > 99 ? 99 : ws_mb;
      v = ldexpf(1.f + (float)wm*(1.f/128.f), 40 + F);
    }
    out[i] = v;
    return;
  }
  const int s = i >> 14, e = (i >> 10) & 15, n = i & 1023;
  float x = 0.f, z = 0.f;
  #pragma unroll
  for (int g=0; g<8; g++){
    const float* oz = OZp + (((long)g*4 + s)*1024 + n)*17;
    x += oz[e];
    z += oz[16];
  }
  float r = x / fmaxf(z, 1e-30f);
  out[i] = 1.f / (1.f + __expf(-r));
}

// ---------------------------------------------------------------------------
extern "C" void kernel_launch(void* const* d_in, const int* in_sizes, int n_in,
                              void* d_out, int out_size, void* d_ws, size_t ws_size,
                              hipStream_t stream)
{
  const void* tgt = d_in[0];
  const void* mem = d_in[1];
  const void* pe  = d_in[2];
  const void* wks = d_in[3];
  const void* bks = d_in[4];
  const void* wkc = d_in[5];
  const void* bkc = d_in[6];
  float* out = (float*)d_out;   // [4][16][1024] FLOAT32 (reference output dtype)

  char* w = (char*)d_ws;
  int*            flags = (int*)w;          w += 256;
  unsigned short* wqS = (unsigned short*)w; w += (size_t)4*1024*128*2;   // 1 MB
  unsigned short* wqC = (unsigned short*)w; w += (size_t)4*1024*128*2;   // 1 MB
  unsigned short* Y   = (unsigned short*)w; w += (size_t)4*512*1024*2;   // 4 MB
  float*          OZ  = (float*)w;          w += (size_t)4*1024*17*4;    // 272 KB
  const size_t NEED = (size_t)(w - (char*)d_ws);

  // OZ partials (8 groups) live in the dead Y buffer during k_crossfuse.
  float* OZp = (float*)Y;                   // 8*4*1024*17*4 = 2228224 B <= 4 MB

  const int detect_ok = ws_size >= 4096;
  const int sane = ws_size >= NEED;

  if (detect_ok)
    hipLaunchKernelGGL(k_detect, dim3(7), dim3(256), 0, stream,
                       tgt, mem, pe, wks, bks, wkc, bkc,
                       in_sizes[0], in_sizes[1], in_sizes[2], in_sizes[3],
                       in_sizes[4], in_sizes[5], in_sizes[6], flags);
  if (sane){
    hipLaunchKernelGGL(k_proj_g, dim3(1024,4), dim3(128), 0, stream,
                       tgt, 0, wks, 3, bks, 4, flags, wqS, 1024);
    hipLaunchKernelGGL(k_self, dim3(1024,4), dim3(256), 0, stream,
                       wqS, tgt, flags, Y);
    hipLaunchKernelGGL(k_inorm, dim3(512,4), dim3(256), 0, stream, Y);
    hipLaunchKernelGGL(k_proj_g, dim3(1024,4), dim3(128), 0, stream,
                       (const void*)Y, -2, wkc, 5, bkc, 6, flags, wqC, 1024);
    // Y is dead from here: reuse as OZ partial buffer.
    hipMemsetAsync(OZp, 0, (size_t)8*4*1024*17*4, stream);
    hipLaunchKernelGGL(k_crossfuse, dim3(128,4), dim3(256), 0, stream,
                       wqC, mem, pe, wkc, bkc, flags, OZp);
  }
  hipLaunchKernelGGL(k_final, dim3(256), dim3(256), 0, stream,
                     (const float*)OZp, out, flags, sane, detect_ok,
                     (int)(ws_size >> 20));
}

// Round 6
// 2289.806 us; speedup vs baseline: 2.7711x; 2.7711x over previous
//
#include <hip/hip_runtime.h>

// LabelPropagator — low-footprint pipeline (6.27 MB ws).
// Inputs runtime-dtype-detected (f32 vs bf16); OUTPUT = FLOAT32 (ref out dtype).
// Shapes: S=4, c=512, kd=128, P=h*w=1024, F=16 (16384 cross keys), ce=16.
//
// R5: MFMA phase B verified correct (passed, MfmaUtil>0). But 17 GB scratch
//     traffic persisted -> found the real correlation: __launch_bounds__(256,2)
//     (R1/R2/R5) => VGPR capped 128 + acc[64] demoted to scratch =>
//     5.7GB FETCH/11.1GB WRITE every time. Plain bounds (R0/R3) => 86MB.
// R6: (a) plain __launch_bounds__(256) on k_crossfuse (the one-token fix);
//     (b) Phase A register retile: thread = 4 keys x 16 dims (acc[4][16]),
//         cutting per-block W L2-reads 33.5MB -> 8.4MB (X gets 4-way reuse);
//         ssred stride-9 padded (stride-8 f32 = 32-way bank conflict).
//     Phase B MFMA frozen from R5.

typedef __attribute__((ext_vector_type(8))) short short8v;
typedef __attribute__((ext_vector_type(4))) short short4v;
typedef __attribute__((ext_vector_type(4))) float float4v;
typedef __attribute__((ext_vector_type(4))) unsigned int uint4v;

__device__ __forceinline__ float b2f(unsigned short h){
  union { unsigned int u; float f; } c; c.u = ((unsigned int)h) << 16; return c.f;
}
__device__ __forceinline__ unsigned short f2b(float f){
  union { float f; unsigned int u; } c; c.f = f;
  unsigned int u = c.u;
  u += 0x7fffu + ((u >> 16) & 1u);     // round-to-nearest-even
  return (unsigned short)(u >> 16);
}
// flag resolve: fi==-1 forced f32, fi==-2 forced bf16, else flags[fi] (1=f32,0=bf16)
__device__ __forceinline__ int getf(const int* flags, int fi){
  return (fi == -1) ? 1 : ((fi == -2) ? 0 : flags[fi]);
}
__device__ __forceinline__ float ld1(const void* p, long i, int f32f){
  return f32f ? ((const float*)p)[i] : b2f(((const unsigned short*)p)[i]);
}
__device__ __forceinline__ void ld8(const void* p, long i, int f32f, float* o){
  if (f32f){
    float4v a = *(const float4v*)((const float*)p + i);
    float4v b = *(const float4v*)((const float*)p + i + 4);
    o[0]=a[0];o[1]=a[1];o[2]=a[2];o[3]=a[3];o[4]=b[0];o[5]=b[1];o[6]=b[2];o[7]=b[3];
  } else {
    short8v v = *(const short8v*)((const unsigned short*)p + i);
    #pragma unroll
    for (int j=0;j<8;j++) o[j] = b2f((unsigned short)v[j]);
  }
}
__device__ __forceinline__ void ld4(const void* p, long i, int f32f, float* o){
  if (f32f){
    float4v a = *(const float4v*)((const float*)p + i);
    o[0]=a[0];o[1]=a[1];o[2]=a[2];o[3]=a[3];
  } else {
    short4v v = *(const short4v*)((const unsigned short*)p + i);
    #pragma unroll
    for (int j=0;j<4;j++) o[j] = b2f((unsigned short)v[j]);
  }
}

__device__ __forceinline__ float4v mfma16(short8v a, short8v b, float4v c){
  return __builtin_amdgcn_mfma_f32_16x16x32_bf16(a, b, c, 0, 0, 0);
}

// ---------------------------------------------------------------------------
// k_detect: flags[i]=1 if input i is f32 (bf16-exponent>=200 rate > 6.25% over
// first min(n,8192) uint16s; f32-as-bf16 gives ~11%, real bf16 data ~0%).
// ---------------------------------------------------------------------------
__global__ __launch_bounds__(256) void k_detect(
    const void* p0, const void* p1, const void* p2, const void* p3,
    const void* p4, const void* p5, const void* p6,
    int n0, int n1, int n2, int n3, int n4, int n5, int n6,
    int* __restrict__ flags)
{
  const int i = blockIdx.x, t = threadIdx.x;
  const void* ps[7] = {p0,p1,p2,p3,p4,p5,p6};
  int ns[7] = {n0,n1,n2,n3,n4,n5,n6};
  const unsigned short* u = (const unsigned short*)ps[i];
  int n = ns[i]; if (n > 8192) n = 8192;
  int cnt = 0;
  for (int k=t; k<n; k+=256){
    int e = (u[k] >> 7) & 0xFF;
    cnt += (e >= 200) ? 1 : 0;
  }
  __shared__ int red[256];
  red[t] = cnt; __syncthreads();
  for (int off=128; off>0; off>>=1){
    if (t < off) red[t] += red[t+off];
    __syncthreads();
  }
  if (t == 0) flags[i] = (red[0]*16 > n) ? 1 : 0;
}

// ---------------------------------------------------------------------------
// k_proj_g: Out[s][n][128] (bf16) = l2norm(X_token(n) @ W^T + b)
// X layout: [(f*4+s)*512 + ch]*1024 + p, f=n>>10, p=n&1023. Block=128 (d).
// ---------------------------------------------------------------------------
__global__ __launch_bounds__(128) void k_proj_g(
    const void* __restrict__ Xv, int xfi,
    const void* __restrict__ Wv, int wfi,
    const void* __restrict__ Bv, int bfi,
    const int* __restrict__ flags,
    unsigned short* __restrict__ Out, int Ntot)
{
  const int n = blockIdx.x, s = blockIdx.y, d = threadIdx.x;
  const int xf = getf(flags,xfi), wf = getf(flags,wfi), bf = getf(flags,bfi);
  const int f = n >> 10, p = n & 1023;
  const long base = ((long)(f*4 + s) * 512) * 1024 + p;
  float acc = ld1(Bv, d, bf);
  const long wbase = (long)d * 512;
  float wv[8];
  for (int ch=0; ch<512; ch+=8){
    ld8(Wv, wbase + ch, wf, wv);
    #pragma unroll
    for (int j=0;j<8;j++)
      acc += ld1(Xv, base + (long)(ch+j)*1024, xf) * wv[j];
  }
  __shared__ float red[128];
  red[d] = acc*acc;
  __syncthreads();
  for (int off=64; off>0; off>>=1){
    if (d < off) red[d] += red[d+off];
    __syncthreads();
  }
  float r = 1.f / fmaxf(sqrtf(fmaxf(red[0], 0.f)), 1e-12f);
  Out[((long)s*Ntot + n)*128 + d] = f2b(acc * r);
}

// ---------------------------------------------------------------------------
// k_self: per (s,n): fixed-shift softmax over 1024 keys (exp(30d-30), diag
// key => Z>=~1; identical to ref softmax), PV over 512 ch, residual add.
// Y[s][ch][n] (bf16) = tgt + attn.
// ---------------------------------------------------------------------------
__global__ __launch_bounds__(256) void k_self(
    const unsigned short* __restrict__ wq,   // [s][1024][128] bf16 (ws)
    const void* __restrict__ tgt,            // [s][512][1024] flagged
    const int* __restrict__ flags,
    unsigned short* __restrict__ Y)          // [s][512][1024] bf16
{
  const int n = blockIdx.x, s = blockIdx.y, t = threadIdx.x;
  const int tf = flags[0];
  __shared__ float qrow[128];
  __shared__ float ps[1024];
  __shared__ float zred[256];
  if (t < 128) qrow[t] = b2f(wq[((long)s*1024 + n)*128 + t]);
  __syncthreads();
  float zp = 0.f;
  #pragma unroll
  for (int kb=0; kb<4; kb++){
    int k = t + kb*256;
    const unsigned short* kr = wq + ((long)s*1024 + k)*128;
    float dot = 0.f;
    for (int d2=0; d2<128; d2+=8){
      short8v kv = *(const short8v*)(kr + d2);
      #pragma unroll
      for (int j=0;j<8;j++) dot += qrow[d2+j] * b2f((unsigned short)kv[j]);
    }
    float pv = __expf(30.f*dot - 30.f);
    ps[k] = pv; zp += pv;
  }
  zred[t] = zp; __syncthreads();
  for (int off=128; off>0; off>>=1){
    if (t < off) zred[t] += zred[t+off];
    __syncthreads();
  }
  float iz = 1.f / fmaxf(zred[0], 1e-30f);
  float vv[8];
  #pragma unroll
  for (int cb=0; cb<2; cb++){
    int ch = t + cb*256;
    const long vrbase = ((long)s*512 + ch)*1024;
    float acc = 0.f;
    for (int k=0; k<1024; k+=8){
      ld8(tgt, vrbase + k, tf, vv);
      #pragma unroll
      for (int j=0;j<8;j++) acc += ps[k+j] * vv[j];
    }
    Y[vrbase + n] = f2b(ld1(tgt, vrbase + n, tf) + acc*iz);
  }
}

// ---------------------------------------------------------------------------
// k_inorm: in-place InstanceNorm (biased var, eps 1e-5) over 1024 tokens.
// ---------------------------------------------------------------------------
__global__ __launch_bounds__(256) void k_inorm(unsigned short* __restrict__ Y)
{
  const int ch = blockIdx.x, s = blockIdx.y, t = threadIdx.x;
  unsigned short* row = Y + ((long)s*512 + ch)*1024;
  float v[4]; float sum=0.f, ss=0.f;
  #pragma unroll
  for (int i=0;i<4;i++){ v[i]=b2f(row[t+256*i]); sum+=v[i]; ss+=v[i]*v[i]; }
  __shared__ float r1[256], r2[256];
  r1[t]=sum; r2[t]=ss; __syncthreads();
  for (int off=128; off>0; off>>=1){
    if (t<off){ r1[t]+=r1[t+off]; r2[t]+=r2[t+off]; }
    __syncthreads();
  }
  float mean = r1[0]*(1.f/1024.f);
  float var  = fmaxf(r2[0]*(1.f/1024.f) - mean*mean, 0.f);
  float rstd = rsqrtf(var + 1e-5f);
  #pragma unroll
  for (int i=0;i<4;i++) row[t+256*i] = f2b((v[i]-mean)*rstd);
}

// ---------------------------------------------------------------------------
// k_crossfuse (R6): block = (key-chunk c, s), 256 threads (4 waves), PLAIN
// launch bounds (min-waves arg caused scratch demotion: R1/R2/R5).
// Chunk = 128 keys of frame f=c>>3 at p0=(c&7)*128. Partial-group grp=c&7.
//
// Phase A (VALU f32, retiled): thread = (kq=t&31 -> keys kq*4..+3,
//   db=t>>5 -> dims db*16..+15), acc[4][16]. 4-key X reuse cuts W L2-reads
//   4x vs R3/R5 (33.5MB -> 8.4MB per block). Bias + per-thread partial ss ->
//   ssred[key][db] (stride 9 to dodge bank conflicts) -> inv per key ->
//   bf16 store to Kl[key][d], XOR swizzle byte = key*256 + ((g*16)^((key&7)<<4))
//   for 16B granule g=d/8 (matches phase B reads).
// Phase A2: PE tile bf16 [e][k], swizzle byte = e*256 + ((k*2)^((e&7)<<4)).
// Phase B (MFMA, per-wave independent, no block barriers; verified R5):
//   PE B-frags (4) hoisted. Wave wv: q-tiles qt=wv,wv+4,..; per q-tile:
//   Q A-frags (4) from global; kt=0..7: 4 x mfma -> S; p=exp(30S-30);
//   z[r]+=p; p->bf16 into per-wave swizzled Pl; 4 mfma P x PE -> O;
//   Z shfl_xor butterfly; atomicAdd O+Z into group partial.
// ---------------------------------------------------------------------------
__global__ __launch_bounds__(256) void k_crossfuse(
    const unsigned short* __restrict__ wqC,  // [s][1024][128] bf16 (ws)
    const void* __restrict__ mem,            // [(f*4+s)*512+ch][1024] flagged
    const void* __restrict__ pe,             // [(f*4+s)*16+e][1024] flagged
    const void* __restrict__ Wv,             // [128][512] flagged
    const void* __restrict__ Bv,             // [128] flagged
    const int* __restrict__ flags,
    float* __restrict__ OZp)                 // [8 grp][4 s][1024][17] f32, zeroed
{
  const int c = blockIdx.x, s = blockIdx.y, t = threadIdx.x;
  const int f = c >> 3, p0 = (c & 7) * 128, grp = c & 7;
  const int mf = flags[1], pf = flags[2], wf = flags[5], bf = flags[6];

  __shared__ unsigned short Kl[128*128];   // 32 KB [key][d] bf16 XOR-swizzled
  __shared__ unsigned short PEb[16*128];   //  4 KB [e][k]  bf16 XOR-swizzled
  __shared__ unsigned short Pl[4*16*128];  // 16 KB per-wave [q][k] bf16 swz
  __shared__ float ssred[128*9];           // 4.5 KB, stride-9 padded

  // ---- Phase A: thread = (key-quad kq, dim-block db): 4 keys x 16 dims
  const int kq = t & 31, db = t >> 5;
  {
    float acc[4][16];
    #pragma unroll
    for (int k=0;k<4;k++)
      #pragma unroll
      for (int d=0;d<16;d++) acc[k][d] = 0.f;
    const long xb = ((long)(f*4 + s) * 512) * 1024 + p0 + kq*4;
    for (int ch=0; ch<512; ch+=8){
      float xv[8][4];
      #pragma unroll
      for (int j=0;j<8;j++)
        ld4(mem, xb + (long)(ch+j)*1024, mf, xv[j]);
      #pragma unroll
      for (int d=0; d<16; d++){
        float wv8[8];
        ld8(Wv, (long)(db*16 + d)*512 + ch, wf, wv8);
        #pragma unroll
        for (int j=0;j<8;j++){
          acc[0][d] += xv[j][0]*wv8[j];
          acc[1][d] += xv[j][1]*wv8[j];
          acc[2][d] += xv[j][2]*wv8[j];
          acc[3][d] += xv[j][3]*wv8[j];
        }
      }
    }
    #pragma unroll
    for (int k=0;k<4;k++){
      float ss = 0.f;
      #pragma unroll
      for (int d=0;d<16;d++){
        acc[k][d] += ld1(Bv, db*16 + d, bf);
        ss += acc[k][d]*acc[k][d];
      }
      ssred[(kq*4 + k)*9 + db] = ss;
    }
    __syncthreads();
    #pragma unroll
    for (int k=0;k<4;k++){
      const int key = kq*4 + k;
      float ssum = 0.f;
      #pragma unroll
      for (int j=0;j<8;j++) ssum += ssred[key*9 + j];
      float inv = 1.f / fmaxf(sqrtf(fmaxf(ssum, 0.f)), 1e-12f);
      char* krow = (char*)Kl + key*256;
      const int xk = (key & 7) << 4;
      #pragma unroll
      for (int gg=0; gg<2; gg++){
        const int g = db*2 + gg;           // 16B granule index (8 dims)
        uint4v v;
        #pragma unroll
        for (int w=0; w<4; w++){
          unsigned int lo = f2b(acc[k][gg*8 + 2*w]   * inv);
          unsigned int hi = f2b(acc[k][gg*8 + 2*w+1] * inv);
          v[w] = lo | (hi << 16);
        }
        *(uint4v*)(krow + ((g*16) ^ xk)) = v;
      }
    }
  }
  // ---- Phase A2: pos_enc tile bf16 [e][k] swizzled; thread t -> e=t>>4,
  //      k0=(t&15)*8 (one b128 per thread covers 16x128)
  {
    const int e = t >> 4, k0 = (t & 15) * 8;
    float pv8[8];
    ld8(pe, ((long)((f*4 + s)*16 + e))*1024 + p0 + k0, pf, pv8);
    uint4v v;
    #pragma unroll
    for (int w=0; w<4; w++){
      unsigned int lo = f2b(pv8[2*w]);
      unsigned int hi = f2b(pv8[2*w+1]);
      v[w] = lo | (hi << 16);
    }
    *(uint4v*)((char*)PEb + e*256 + (((k0*2)) ^ ((e & 7) << 4))) = v;
  }
  __syncthreads();

  // ---- Phase B: MFMA, waves independent (frozen from R5)
  const int l = t & 63, wv = t >> 6;
  const int lr = l & 15, lg = l >> 4;      // frag 16-dim index / k-group
  char* PlW = (char*)Pl + wv*4096;         // per-wave P tile

  // PE B-frags: lane l holds PE[k=(lg*8..+7)+kb*32][e=lr]
  short8v peb[4];
  #pragma unroll
  for (int kb=0; kb<4; kb++){
    const int k0 = kb*32 + lg*8;
    peb[kb] = *(const short8v*)((char*)PEb + lr*256 + ((k0*2) ^ ((lr & 7) << 4)));
  }

  for (int qt = wv; qt < 64; qt += 4){
    // Q A-frags: lane l holds Q[q=qt*16+lr][k=kb*32+lg*8 ..+7]
    short8v qf[4];
    const unsigned short* qbase = wqC + ((long)s*1024 + qt*16 + lr)*128;
    #pragma unroll
    for (int kb=0; kb<4; kb++)
      qf[kb] = *(const short8v*)(qbase + kb*32 + lg*8);

    float zacc[4] = {0.f, 0.f, 0.f, 0.f};
    #pragma unroll 1
    for (int kt=0; kt<8; ++kt){
      float4v sacc = {0.f, 0.f, 0.f, 0.f};
      const int key = kt*16 + lr;
      const char* krow = (const char*)Kl + key*256;
      const int xk = (key & 7) << 4;
      #pragma unroll
      for (int kb=0; kb<4; kb++){
        short8v kf = *(const short8v*)(krow + (((kb*32 + lg*8)*2) ^ xk));
        sacc = mfma16(qf[kb], kf, sacc);
      }
      // S -> P (C-layout: col=key=lr, row q=lg*4+r), scatter to Pl
      #pragma unroll
      for (int r=0; r<4; r++){
        float p = __expf(30.f*sacc[r] - 30.f);
        zacc[r] += p;
        const int q = lg*4 + r;
        *(unsigned short*)(PlW + q*256 + (((kt*16 + lr)*2) ^ ((q & 7) << 4))) = f2b(p);
      }
    }
    // PV: P A-frags (lane: row q=lr, k=kb*32+lg*8..+7) x PE B-frags
    float4v pv = {0.f, 0.f, 0.f, 0.f};
    #pragma unroll
    for (int kb=0; kb<4; kb++){
      const int k0 = kb*32 + lg*8;
      short8v pf8 = *(const short8v*)(PlW + lr*256 + ((k0*2) ^ ((lr & 7) << 4)));
      pv = mfma16(pf8, peb[kb], pv);
    }
    // Z: butterfly over the 16 cols (lanes lr=0..15 within group)
    #pragma unroll
    for (int r=0; r<4; r++){
      float z = zacc[r];
      z += __shfl_xor(z, 1);
      z += __shfl_xor(z, 2);
      z += __shfl_xor(z, 4);
      z += __shfl_xor(z, 8);
      zacc[r] = z;
    }
    float* oz = OZp + ((((long)grp*4 + s)*1024) + qt*16)*17;
    #pragma unroll
    for (int r=0; r<4; r++)
      atomicAdd(&oz[(lg*4 + r)*17 + lr], pv[r]);
    if (lr == 0){
      #pragma unroll
      for (int r=0; r<4; r++)
        atomicAdd(&oz[(lg*4 + r)*17 + 16], zacc[r]);
    }
  }
}

// ---------------------------------------------------------------------------
// k_final: out (FLOAT32) = sigmoid(O/Z) summing 8 group partials; diagnostic
// if ws too small. out[i], i = ((s*16+e)<<10)+n.
// ---------------------------------------------------------------------------
__global__ __launch_bounds__(256) void k_final(
    const float* __restrict__ OZp, float* __restrict__ out,
    const int* __restrict__ flags, int sane, int detect_ok, int ws_mb)
{
  const int i = blockIdx.x*256 + threadIdx.x;   // 0..65535
  if (!sane){
    float v = 0.5f;
    if (i == 0){
      int F = 0;
      if (detect_ok)
        F = flags[0]*16 + flags[1]*8 + flags[2]*4 + flags[3]*2 + flags[5];
      int wm = ws_mb > 99 ? 99 : ws_mb;
      v = ldexpf(1.f + (float)wm*(1.f/128.f), 40 + F);
    }
    out[i] = v;
    return;
  }
  const int s = i >> 14, e = (i >> 10) & 15, n = i & 1023;
  float x = 0.f, z = 0.f;
  #pragma unroll
  for (int g=0; g<8; g++){
    const float* oz = OZp + (((long)g*4 + s)*1024 + n)*17;
    x += oz[e];
    z += oz[16];
  }
  float r = x / fmaxf(z, 1e-30f);
  out[i] = 1.f / (1.f + __expf(-r));
}

// ---------------------------------------------------------------------------
extern "C" void kernel_launch(void* const* d_in, const int* in_sizes, int n_in,
                              void* d_out, int out_size, void* d_ws, size_t ws_size,
                              hipStream_t stream)
{
  const void* tgt = d_in[0];
  const void* mem = d_in[1];
  const void* pe  = d_in[2];
  const void* wks = d_in[3];
  const void* bks = d_in[4];
  const void* wkc = d_in[5];
  const void* bkc = d_in[6];
  float* out = (float*)d_out;   // [4][16][1024] FLOAT32 (reference output dtype)

  char* w = (char*)d_ws;
  int*            flags = (int*)w;          w += 256;
  unsigned short* wqS = (unsigned short*)w; w += (size_t)4*1024*128*2;   // 1 MB
  unsigned short* wqC = (unsigned short*)w; w += (size_t)4*1024*128*2;   // 1 MB
  unsigned short* Y   = (unsigned short*)w; w += (size_t)4*512*1024*2;   // 4 MB
  float*          OZ  = (float*)w;          w += (size_t)4*1024*17*4;    // 272 KB
  const size_t NEED = (size_t)(w - (char*)d_ws);

  // OZ partials (8 groups) live in the dead Y buffer during k_crossfuse.
  float* OZp = (float*)Y;                   // 8*4*1024*17*4 = 2228224 B <= 4 MB

  const int detect_ok = ws_size >= 4096;
  const int sane = ws_size >= NEED;

  if (detect_ok)
    hipLaunchKernelGGL(k_detect, dim3(7), dim3(256), 0, stream,
                       tgt, mem, pe, wks, bks, wkc, bkc,
                       in_sizes[0], in_sizes[1], in_sizes[2], in_sizes[3],
                       in_sizes[4], in_sizes[5], in_sizes[6], flags);
  if (sane){
    hipLaunchKernelGGL(k_proj_g, dim3(1024,4), dim3(128), 0, stream,
                       tgt, 0, wks, 3, bks, 4, flags, wqS, 1024);
    hipLaunchKernelGGL(k_self, dim3(1024,4), dim3(256), 0, stream,
                       wqS, tgt, flags, Y);
    hipLaunchKernelGGL(k_inorm, dim3(512,4), dim3(256), 0, stream, Y);
    hipLaunchKernelGGL(k_proj_g, dim3(1024,4), dim3(128), 0, stream,
                       (const void*)Y, -2, wkc, 5, bkc, 6, flags, wqC, 1024);
    // Y is dead from here: reuse as OZ partial buffer.
    hipMemsetAsync(OZp, 0, (size_t)8*4*1024*17*4, stream);
    hipLaunchKernelGGL(k_crossfuse, dim3(128,4), dim3(256), 0, stream,
                       wqC, mem, pe, wkc, bkc, flags, OZp);
  }
  hipLaunchKernelGGL(k_final, dim3(256), dim3(256), 0, stream,
                     (const float*)OZp, out, flags, sane, detect_ok,
                     (int)(ws_size >> 20));
}

// Round 7
// 1251.353 us; speedup vs baseline: 5.0707x; 1.8299x over previous
//
#include <hip/hip_runtime.h>

// LabelPropagator — low-footprint pipeline (6.27 MB ws).
// Inputs runtime-dtype-detected (f32 vs bf16); OUTPUT = FLOAT32 (ref out dtype).
// Shapes: S=4, c=512, kd=128, P=h*w=1024, F=16 (16384 cross keys), ce=16.
//
// R6 (verified): plain __launch_bounds__ fixed the scratch demotion
//     (__launch_bounds__(256,2) made the backend spill acc[] -> 17.6 GB);
//     total 6345 -> 2290 us, crossfuse off the top-5.
// R7: k_self (1238 us, latency-bound VALU: VALUBusy 12%, Occ 12%, HBM 0.7%)
//     rewritten on MFMA with the crossfuse-verified fragment/swizzle scheme.
//     Block = (q-tile 16, s), 4 waves x 128 ch. K/Q/V read direct from global
//     (wqS rows and tgt's [ch][n] layout are exactly frag-shaped). V split
//     hi/lo bf16 (2 MFMAs, error ~2^-17: no precision regression vs f32 V).
//     Z accumulated from ROUNDED P (consistent with bf16 numerator).
//     Residual add fused into the epilogue.

typedef __attribute__((ext_vector_type(8))) short short8v;
typedef __attribute__((ext_vector_type(4))) short short4v;
typedef __attribute__((ext_vector_type(4))) float float4v;
typedef __attribute__((ext_vector_type(4))) unsigned int uint4v;

__device__ __forceinline__ float b2f(unsigned short h){
  union { unsigned int u; float f; } c; c.u = ((unsigned int)h) << 16; return c.f;
}
__device__ __forceinline__ unsigned short f2b(float f){
  union { float f; unsigned int u; } c; c.f = f;
  unsigned int u = c.u;
  u += 0x7fffu + ((u >> 16) & 1u);     // round-to-nearest-even
  return (unsigned short)(u >> 16);
}
// flag resolve: fi==-1 forced f32, fi==-2 forced bf16, else flags[fi] (1=f32,0=bf16)
__device__ __forceinline__ int getf(const int* flags, int fi){
  return (fi == -1) ? 1 : ((fi == -2) ? 0 : flags[fi]);
}
__device__ __forceinline__ float ld1(const void* p, long i, int f32f){
  return f32f ? ((const float*)p)[i] : b2f(((const unsigned short*)p)[i]);
}
__device__ __forceinline__ void ld8(const void* p, long i, int f32f, float* o){
  if (f32f){
    float4v a = *(const float4v*)((const float*)p + i);
    float4v b = *(const float4v*)((const float*)p + i + 4);
    o[0]=a[0];o[1]=a[1];o[2]=a[2];o[3]=a[3];o[4]=b[0];o[5]=b[1];o[6]=b[2];o[7]=b[3];
  } else {
    short8v v = *(const short8v*)((const unsigned short*)p + i);
    #pragma unroll
    for (int j=0;j<8;j++) o[j] = b2f((unsigned short)v[j]);
  }
}
__device__ __forceinline__ void ld4(const void* p, long i, int f32f, float* o){
  if (f32f){
    float4v a = *(const float4v*)((const float*)p + i);
    o[0]=a[0];o[1]=a[1];o[2]=a[2];o[3]=a[3];
  } else {
    short4v v = *(const short4v*)((const unsigned short*)p + i);
    #pragma unroll
    for (int j=0;j<4;j++) o[j] = b2f((unsigned short)v[j]);
  }
}

__device__ __forceinline__ float4v mfma16(short8v a, short8v b, float4v c){
  return __builtin_amdgcn_mfma_f32_16x16x32_bf16(a, b, c, 0, 0, 0);
}

// ---------------------------------------------------------------------------
// k_detect: flags[i]=1 if input i is f32 (bf16-exponent>=200 rate > 6.25% over
// first min(n,8192) uint16s; f32-as-bf16 gives ~11%, real bf16 data ~0%).
// ---------------------------------------------------------------------------
__global__ __launch_bounds__(256) void k_detect(
    const void* p0, const void* p1, const void* p2, const void* p3,
    const void* p4, const void* p5, const void* p6,
    int n0, int n1, int n2, int n3, int n4, int n5, int n6,
    int* __restrict__ flags)
{
  const int i = blockIdx.x, t = threadIdx.x;
  const void* ps[7] = {p0,p1,p2,p3,p4,p5,p6};
  int ns[7] = {n0,n1,n2,n3,n4,n5,n6};
  const unsigned short* u = (const unsigned short*)ps[i];
  int n = ns[i]; if (n > 8192) n = 8192;
  int cnt = 0;
  for (int k=t; k<n; k+=256){
    int e = (u[k] >> 7) & 0xFF;
    cnt += (e >= 200) ? 1 : 0;
  }
  __shared__ int red[256];
  red[t] = cnt; __syncthreads();
  for (int off=128; off>0; off>>=1){
    if (t < off) red[t] += red[t+off];
    __syncthreads();
  }
  if (t == 0) flags[i] = (red[0]*16 > n) ? 1 : 0;
}

// ---------------------------------------------------------------------------
// k_proj_g: Out[s][n][128] (bf16) = l2norm(X_token(n) @ W^T + b)
// X layout: [(f*4+s)*512 + ch]*1024 + p, f=n>>10, p=n&1023. Block=128 (d).
// ---------------------------------------------------------------------------
__global__ __launch_bounds__(128) void k_proj_g(
    const void* __restrict__ Xv, int xfi,
    const void* __restrict__ Wv, int wfi,
    const void* __restrict__ Bv, int bfi,
    const int* __restrict__ flags,
    unsigned short* __restrict__ Out, int Ntot)
{
  const int n = blockIdx.x, s = blockIdx.y, d = threadIdx.x;
  const int xf = getf(flags,xfi), wf = getf(flags,wfi), bf = getf(flags,bfi);
  const int f = n >> 10, p = n & 1023;
  const long base = ((long)(f*4 + s) * 512) * 1024 + p;
  float acc = ld1(Bv, d, bf);
  const long wbase = (long)d * 512;
  float wv[8];
  for (int ch=0; ch<512; ch+=8){
    ld8(Wv, wbase + ch, wf, wv);
    #pragma unroll
    for (int j=0;j<8;j++)
      acc += ld1(Xv, base + (long)(ch+j)*1024, xf) * wv[j];
  }
  __shared__ float red[128];
  red[d] = acc*acc;
  __syncthreads();
  for (int off=64; off>0; off>>=1){
    if (d < off) red[d] += red[d+off];
    __syncthreads();
  }
  float r = 1.f / fmaxf(sqrtf(fmaxf(red[0], 0.f)), 1e-12f);
  Out[((long)s*Ntot + n)*128 + d] = f2b(acc * r);
}

// ---------------------------------------------------------------------------
// k_self (R7, MFMA): block = (q-tile n0=16*bx, s), 256 threads (4 waves).
// Wave w owns channels w*128..w*128+127. Fixed-shift softmax exp(30d-30)
// (diag key => Z>=~1, matches ref softmax exactly as before).
//
// Per key-chunk kc (128 keys):
//   scores: wave w computes key-subtiles w*2, w*2+1: 4 MFMA each
//     (Q A-frags preloaded; K B-frags direct from wqS rows, contiguous).
//     p = exp(30S-30) -> bf16 -> swizzled Pl[q][kk]; Z += rounded p.
//   PV: P A-frags (4) from Pl; V B-frags DIRECT from tgt [ch][n] layout
//     (per-lane contiguous along n=key for fixed ch). f32 inputs split
//     hi/lo bf16 -> two MFMAs into the same accumulator (exact to ~2^-17).
// Epilogue: Z shfl_xor butterfly + cross-wave LDS sum; Y = tgt + O/Z (bf16).
// ---------------------------------------------------------------------------
__global__ __launch_bounds__(256) void k_self(
    const unsigned short* __restrict__ wq,   // [s][1024][128] bf16 (ws)
    const void* __restrict__ tgt,            // [s][512][1024] flagged
    const int* __restrict__ flags,
    unsigned short* __restrict__ Y)          // [s][512][1024] bf16
{
  const int n0 = blockIdx.x * 16, s = blockIdx.y, t = threadIdx.x;
  const int tf = flags[0];
  const int l = t & 63, w = t >> 6;
  const int lr = l & 15, lg = l >> 4;

  __shared__ unsigned short Pl[16*128];    // 4 KB [q][kk] bf16, row-swizzled
  __shared__ float zl[4*16];               // [wave][q]

  // Q A-frags: lane: row q=lr, k=d=kb*32+lg*8 (contiguous)
  short8v qf[4];
  {
    const unsigned short* qbase = wq + ((long)s*1024 + n0 + lr)*128;
    #pragma unroll
    for (int kb=0; kb<4; kb++)
      qf[kb] = *(const short8v*)(qbase + kb*32 + lg*8);
  }

  float4v Ofr[8];                          // ch-tiles: ch = w*128 + ct*16 + lr
  #pragma unroll
  for (int ct=0; ct<8; ct++) Ofr[ct] = (float4v){0.f,0.f,0.f,0.f};
  float zacc[4] = {0.f,0.f,0.f,0.f};

  #pragma unroll 1
  for (int kc=0; kc<8; ++kc){
    // ---- scores: wave w -> key-subtiles (w*2), (w*2+1)
    #pragma unroll
    for (int kss=0; kss<2; kss++){
      const int kk0 = (w*2 + kss)*16;                // key within chunk
      const unsigned short* kb_ = wq + ((long)s*1024 + kc*128 + kk0 + lr)*128;
      float4v sacc = {0.f,0.f,0.f,0.f};
      #pragma unroll
      for (int kb=0; kb<4; kb++){
        short8v kf = *(const short8v*)(kb_ + kb*32 + lg*8);
        sacc = mfma16(qf[kb], kf, sacc);
      }
      #pragma unroll
      for (int r=0; r<4; r++){
        float p = __expf(30.f*sacc[r] - 30.f);
        unsigned short pb = f2b(p);
        zacc[r] += b2f(pb);                          // Z consistent with bf16 P
        const int q = lg*4 + r;
        const int kk = kk0 + lr;
        *(unsigned short*)((char*)Pl + q*256 + (((kk*2)) ^ ((q&7)<<4))) = pb;
      }
    }
    __syncthreads();
    // ---- PV: A = P frags, B = V frags direct from tgt
    short8v pfr[4];
    #pragma unroll
    for (int kt=0; kt<4; kt++){
      const int k0 = kt*32 + lg*8;
      pfr[kt] = *(const short8v*)((char*)Pl + lr*256 + ((k0*2) ^ ((lr&7)<<4)));
    }
    if (tf){
      #pragma unroll
      for (int ct=0; ct<8; ct++){
        const int ch = w*128 + ct*16 + lr;
        const float* vb = (const float*)tgt + ((long)s*512 + ch)*1024 + kc*128;
        #pragma unroll
        for (int kt=0; kt<4; kt++){
          float4v a = *(const float4v*)(vb + kt*32 + lg*8);
          float4v b = *(const float4v*)(vb + kt*32 + lg*8 + 4);
          float v8[8] = {a[0],a[1],a[2],a[3],b[0],b[1],b[2],b[3]};
          short8v vh, vl;
          #pragma unroll
          for (int j=0;j<8;j++){
            unsigned short h = f2b(v8[j]);
            vh[j] = (short)h;
            vl[j] = (short)f2b(v8[j] - b2f(h));
          }
          Ofr[ct] = mfma16(pfr[kt], vh, Ofr[ct]);
          Ofr[ct] = mfma16(pfr[kt], vl, Ofr[ct]);
        }
      }
    } else {
      #pragma unroll
      for (int ct=0; ct<8; ct++){
        const int ch = w*128 + ct*16 + lr;
        const unsigned short* vb = (const unsigned short*)tgt
                                   + ((long)s*512 + ch)*1024 + kc*128;
        #pragma unroll
        for (int kt=0; kt<4; kt++){
          short8v vv = *(const short8v*)(vb + kt*32 + lg*8);
          Ofr[ct] = mfma16(pfr[kt], vv, Ofr[ct]);
        }
      }
    }
    __syncthreads();
  }

  // ---- Z: butterfly over the 16 key-cols, then cross-wave sum via LDS
  #pragma unroll
  for (int r=0; r<4; r++){
    float z = zacc[r];
    z += __shfl_xor(z, 1);
    z += __shfl_xor(z, 2);
    z += __shfl_xor(z, 4);
    z += __shfl_xor(z, 8);
    zacc[r] = z;
  }
  if (lr == 0){
    #pragma unroll
    for (int r=0; r<4; r++) zl[w*16 + lg*4 + r] = zacc[r];
  }
  __syncthreads();
  float izq[4];
  #pragma unroll
  for (int r=0; r<4; r++){
    const int q = lg*4 + r;
    float z = zl[q] + zl[16+q] + zl[32+q] + zl[48+q];
    izq[r] = 1.f / fmaxf(z, 1e-30f);
  }
  // ---- epilogue: Y = tgt + O/Z (lane: ch fixed, 4 consecutive n)
  #pragma unroll
  for (int ct=0; ct<8; ct++){
    const int ch = w*128 + ct*16 + lr;
    const long base = ((long)s*512 + ch)*1024 + n0 + lg*4;
    float tv[4];
    ld4(tgt, base, tf, tv);
    short4v ob;
    #pragma unroll
    for (int r=0; r<4; r++)
      ob[r] = (short)f2b(tv[r] + Ofr[ct][r]*izq[r]);
    *(short4v*)(Y + base) = ob;
  }
}

// ---------------------------------------------------------------------------
// k_inorm: in-place InstanceNorm (biased var, eps 1e-5) over 1024 tokens.
// ---------------------------------------------------------------------------
__global__ __launch_bounds__(256) void k_inorm(unsigned short* __restrict__ Y)
{
  const int ch = blockIdx.x, s = blockIdx.y, t = threadIdx.x;
  unsigned short* row = Y + ((long)s*512 + ch)*1024;
  float v[4]; float sum=0.f, ss=0.f;
  #pragma unroll
  for (int i=0;i<4;i++){ v[i]=b2f(row[t+256*i]); sum+=v[i]; ss+=v[i]*v[i]; }
  __shared__ float r1[256], r2[256];
  r1[t]=sum; r2[t]=ss; __syncthreads();
  for (int off=128; off>0; off>>=1){
    if (t<off){ r1[t]+=r1[t+off]; r2[t]+=r2[t+off]; }
    __syncthreads();
  }
  float mean = r1[0]*(1.f/1024.f);
  float var  = fmaxf(r2[0]*(1.f/1024.f) - mean*mean, 0.f);
  float rstd = rsqrtf(var + 1e-5f);
  #pragma unroll
  for (int i=0;i<4;i++) row[t+256*i] = f2b((v[i]-mean)*rstd);
}

// ---------------------------------------------------------------------------
// k_crossfuse (R6, verified): block = (key-chunk c, s), 256 threads, PLAIN
// launch bounds. Chunk = 128 keys of frame f=c>>3 at p0=(c&7)*128.
// Phase A: thread = (kq=t&31 -> 4 keys, db=t>>5 -> 16 dims), acc[4][16];
//   ssred stride-9; bf16 store to Kl XOR-swizzled.
// Phase B (MFMA): PE B-frags hoisted; per q-tile: Q A-frags from global;
//   8 key-subtiles x 4 MFMA -> S; p=exp(30S-30); P -> swizzled Pl; 4 MFMA
//   P x PE -> O; Z butterfly; atomicAdd into group partials (grp=c&7).
// ---------------------------------------------------------------------------
__global__ __launch_bounds__(256) void k_crossfuse(
    const unsigned short* __restrict__ wqC,  // [s][1024][128] bf16 (ws)
    const void* __restrict__ mem,            // [(f*4+s)*512+ch][1024] flagged
    const void* __restrict__ pe,             // [(f*4+s)*16+e][1024] flagged
    const void* __restrict__ Wv,             // [128][512] flagged
    const void* __restrict__ Bv,             // [128] flagged
    const int* __restrict__ flags,
    float* __restrict__ OZp)                 // [8 grp][4 s][1024][17] f32, zeroed
{
  const int c = blockIdx.x, s = blockIdx.y, t = threadIdx.x;
  const int f = c >> 3, p0 = (c & 7) * 128, grp = c & 7;
  const int mf = flags[1], pf = flags[2], wf = flags[5], bf = flags[6];

  __shared__ unsigned short Kl[128*128];   // 32 KB [key][d] bf16 XOR-swizzled
  __shared__ unsigned short PEb[16*128];   //  4 KB [e][k]  bf16 XOR-swizzled
  __shared__ unsigned short Pl[4*16*128];  // 16 KB per-wave [q][k] bf16 swz
  __shared__ float ssred[128*9];           // 4.5 KB, stride-9 padded

  // ---- Phase A: thread = (key-quad kq, dim-block db): 4 keys x 16 dims
  const int kq = t & 31, db = t >> 5;
  {
    float acc[4][16];
    #pragma unroll
    for (int k=0;k<4;k++)
      #pragma unroll
      for (int d=0;d<16;d++) acc[k][d] = 0.f;
    const long xb = ((long)(f*4 + s) * 512) * 1024 + p0 + kq*4;
    for (int ch=0; ch<512; ch+=8){
      float xv[8][4];
      #pragma unroll
      for (int j=0;j<8;j++)
        ld4(mem, xb + (long)(ch+j)*1024, mf, xv[j]);
      #pragma unroll
      for (int d=0; d<16; d++){
        float wv8[8];
        ld8(Wv, (long)(db*16 + d)*512 + ch, wf, wv8);
        #pragma unroll
        for (int j=0;j<8;j++){
          acc[0][d] += xv[j][0]*wv8[j];
          acc[1][d] += xv[j][1]*wv8[j];
          acc[2][d] += xv[j][2]*wv8[j];
          acc[3][d] += xv[j][3]*wv8[j];
        }
      }
    }
    #pragma unroll
    for (int k=0;k<4;k++){
      float ss = 0.f;
      #pragma unroll
      for (int d=0;d<16;d++){
        acc[k][d] += ld1(Bv, db*16 + d, bf);
        ss += acc[k][d]*acc[k][d];
      }
      ssred[(kq*4 + k)*9 + db] = ss;
    }
    __syncthreads();
    #pragma unroll
    for (int k=0;k<4;k++){
      const int key = kq*4 + k;
      float ssum = 0.f;
      #pragma unroll
      for (int j=0;j<8;j++) ssum += ssred[key*9 + j];
      float inv = 1.f / fmaxf(sqrtf(fmaxf(ssum, 0.f)), 1e-12f);
      char* krow = (char*)Kl + key*256;
      const int xk = (key & 7) << 4;
      #pragma unroll
      for (int gg=0; gg<2; gg++){
        const int g = db*2 + gg;           // 16B granule index (8 dims)
        uint4v v;
        #pragma unroll
        for (int w=0; w<4; w++){
          unsigned int lo = f2b(acc[k][gg*8 + 2*w]   * inv);
          unsigned int hi = f2b(acc[k][gg*8 + 2*w+1] * inv);
          v[w] = lo | (hi << 16);
        }
        *(uint4v*)(krow + ((g*16) ^ xk)) = v;
      }
    }
  }
  // ---- Phase A2: pos_enc tile bf16 [e][k] swizzled; thread t -> e=t>>4,
  //      k0=(t&15)*8 (one b128 per thread covers 16x128)
  {
    const int e = t >> 4, k0 = (t & 15) * 8;
    float pv8[8];
    ld8(pe, ((long)((f*4 + s)*16 + e))*1024 + p0 + k0, pf, pv8);
    uint4v v;
    #pragma unroll
    for (int w=0; w<4; w++){
      unsigned int lo = f2b(pv8[2*w]);
      unsigned int hi = f2b(pv8[2*w+1]);
      v[w] = lo | (hi << 16);
    }
    *(uint4v*)((char*)PEb + e*256 + (((k0*2)) ^ ((e & 7) << 4))) = v;
  }
  __syncthreads();

  // ---- Phase B: MFMA, waves independent (frozen from R5/R6)
  const int l = t & 63, wv = t >> 6;
  const int lr = l & 15, lg = l >> 4;      // frag 16-dim index / k-group
  char* PlW = (char*)Pl + wv*4096;         // per-wave P tile

  // PE B-frags: lane l holds PE[k=(lg*8..+7)+kb*32][e=lr]
  short8v peb[4];
  #pragma unroll
  for (int kb=0; kb<4; kb++){
    const int k0 = kb*32 + lg*8;
    peb[kb] = *(const short8v*)((char*)PEb + lr*256 + ((k0*2) ^ ((lr & 7) << 4)));
  }

  for (int qt = wv; qt < 64; qt += 4){
    // Q A-frags: lane l holds Q[q=qt*16+lr][k=kb*32+lg*8 ..+7]
    short8v qf[4];
    const unsigned short* qbase = wqC + ((long)s*1024 + qt*16 + lr)*128;
    #pragma unroll
    for (int kb=0; kb<4; kb++)
      qf[kb] = *(const short8v*)(qbase + kb*32 + lg*8);

    float zacc[4] = {0.f, 0.f, 0.f, 0.f};
    #pragma unroll 1
    for (int kt=0; kt<8; ++kt){
      float4v sacc = {0.f, 0.f, 0.f, 0.f};
      const int key = kt*16 + lr;
      const char* krow = (const char*)Kl + key*256;
      const int xk = (key & 7) << 4;
      #pragma unroll
      for (int kb=0; kb<4; kb++){
        short8v kf = *(const short8v*)(krow + (((kb*32 + lg*8)*2) ^ xk));
        sacc = mfma16(qf[kb], kf, sacc);
      }
      // S -> P (C-layout: col=key=lr, row q=lg*4+r), scatter to Pl
      #pragma unroll
      for (int r=0; r<4; r++){
        float p = __expf(30.f*sacc[r] - 30.f);
        zacc[r] += p;
        const int q = lg*4 + r;
        *(unsigned short*)(PlW + q*256 + (((kt*16 + lr)*2) ^ ((q & 7) << 4))) = f2b(p);
      }
    }
    // PV: P A-frags (lane: row q=lr, k=kb*32+lg*8..+7) x PE B-frags
    float4v pv = {0.f, 0.f, 0.f, 0.f};
    #pragma unroll
    for (int kb=0; kb<4; kb++){
      const int k0 = kb*32 + lg*8;
      short8v pf8 = *(const short8v*)(PlW + lr*256 + ((k0*2) ^ ((lr & 7) << 4)));
      pv = mfma16(pf8, peb[kb], pv);
    }
    // Z: butterfly over the 16 cols (lanes lr=0..15 within group)
    #pragma unroll
    for (int r=0; r<4; r++){
      float z = zacc[r];
      z += __shfl_xor(z, 1);
      z += __shfl_xor(z, 2);
      z += __shfl_xor(z, 4);
      z += __shfl_xor(z, 8);
      zacc[r] = z;
    }
    float* oz = OZp + ((((long)grp*4 + s)*1024) + qt*16)*17;
    #pragma unroll
    for (int r=0; r<4; r++)
      atomicAdd(&oz[(lg*4 + r)*17 + lr], pv[r]);
    if (lr == 0){
      #pragma unroll
      for (int r=0; r<4; r++)
        atomicAdd(&oz[(lg*4 + r)*17 + 16], zacc[r]);
    }
  }
}

// ---------------------------------------------------------------------------
// k_final: out (FLOAT32) = sigmoid(O/Z) summing 8 group partials; diagnostic
// if ws too small. out[i], i = ((s*16+e)<<10)+n.
// ---------------------------------------------------------------------------
__global__ __launch_bounds__(256) void k_final(
    const float* __restrict__ OZp, float* __restrict__ out,
    const int* __restrict__ flags, int sane, int detect_ok, int ws_mb)
{
  const int i = blockIdx.x*256 + threadIdx.x;   // 0..65535
  if (!sane){
    float v = 0.5f;
    if (i == 0){
      int F = 0;
      if (detect_ok)
        F = flags[0]*16 + flags[1]*8 + flags[2]*4 + flags[3]*2 + flags[5];
      int wm = ws_mb > 99 ? 99 : ws_mb;
      v = ldexpf(1.f + (float)wm*(1.f/128.f), 40 + F);
    }
    out[i] = v;
    return;
  }
  const int s = i >> 14, e = (i >> 10) & 15, n = i & 1023;
  float x = 0.f, z = 0.f;
  #pragma unroll
  for (int g=0; g<8; g++){
    const float* oz = OZp + (((long)g*4 + s)*1024 + n)*17;
    x += oz[e];
    z += oz[16];
  }
  float r = x / fmaxf(z, 1e-30f);
  out[i] = 1.f / (1.f + __expf(-r));
}

// ---------------------------------------------------------------------------
extern "C" void kernel_launch(void* const* d_in, const int* in_sizes, int n_in,
                              void* d_out, int out_size, void* d_ws, size_t ws_size,
                              hipStream_t stream)
{
  const void* tgt = d_in[0];
  const void* mem = d_in[1];
  const void* pe  = d_in[2];
  const void* wks = d_in[3];
  const void* bks = d_in[4];
  const void* wkc = d_in[5];
  const void* bkc = d_in[6];
  float* out = (float*)d_out;   // [4][16][1024] FLOAT32 (reference output dtype)

  char* w = (char*)d_ws;
  int*            flags = (int*)w;          w += 256;
  unsigned short* wqS = (unsigned short*)w; w += (size_t)4*1024*128*2;   // 1 MB
  unsigned short* wqC = (unsigned short*)w; w += (size_t)4*1024*128*2;   // 1 MB
  unsigned short* Y   = (unsigned short*)w; w += (size_t)4*512*1024*2;   // 4 MB
  float*          OZ  = (float*)w;          w += (size_t)4*1024*17*4;    // 272 KB
  const size_t NEED = (size_t)(w - (char*)d_ws);

  // OZ partials (8 groups) live in the dead Y buffer during k_crossfuse.
  float* OZp = (float*)Y;                   // 8*4*1024*17*4 = 2228224 B <= 4 MB

  const int detect_ok = ws_size >= 4096;
  const int sane = ws_size >= NEED;

  if (detect_ok)
    hipLaunchKernelGGL(k_detect, dim3(7), dim3(256), 0, stream,
                       tgt, mem, pe, wks, bks, wkc, bkc,
                       in_sizes[0], in_sizes[1], in_sizes[2], in_sizes[3],
                       in_sizes[4], in_sizes[5], in_sizes[6], flags);
  if (sane){
    hipLaunchKernelGGL(k_proj_g, dim3(1024,4), dim3(128), 0, stream,
                       tgt, 0, wks, 3, bks, 4, flags, wqS, 1024);
    hipLaunchKernelGGL(k_self, dim3(64,4), dim3(256), 0, stream,
                       wqS, tgt, flags, Y);
    hipLaunchKernelGGL(k_inorm, dim3(512,4), dim3(256), 0, stream, Y);
    hipLaunchKernelGGL(k_proj_g, dim3(1024,4), dim3(128), 0, stream,
                       (const void*)Y, -2, wkc, 5, bkc, 6, flags, wqC, 1024);
    // Y is dead from here: reuse as OZ partial buffer.
    hipMemsetAsync(OZp, 0, (size_t)8*4*1024*17*4, stream);
    hipLaunchKernelGGL(k_crossfuse, dim3(128,4), dim3(256), 0, stream,
                       wqC, mem, pe, wkc, bkc, flags, OZp);
  }
  hipLaunchKernelGGL(k_final, dim3(256), dim3(256), 0, stream,
                     (const float*)OZp, out, flags, sane, detect_ok,
                     (int)(ws_size >> 20));
}

// Round 9
// 887.973 us; speedup vs baseline: 7.1458x; 1.4092x over previous
//
#include <hip/hip_runtime.h>

// LabelPropagator — low-footprint pipeline (6.27 MB ws).
// Inputs runtime-dtype-detected (f32 vs bf16); OUTPUT = FLOAT32 (ref out dtype).
// Shapes: S=4, c=512, kd=128, P=h*w=1024, F=16 (16384 cross keys), ce=16.
//
// R6 (verified): NEVER pass a min-waves arg to __launch_bounds__ here — the
//     backend pre-commits big per-thread arrays to scratch (17.6 GB traffic).
// R7 (verified): k_self on MFMA; total 2290 -> 1251 us.
// R8: k_crossfuse phase A (projection GEMM, was VALU: 35K instr/wave, 2
//     waves/SIMD, 75% latency stalls -> 500 us) moved to MFMA:
//     D[dim][key] = W x X^T. A = W rows hi/lo bf16 (direct global, ch-contig);
//     B = X^T tile per 32-ch chunk in LDS (hi/lo, [key][plane][ch] 128B rows,
//     granule XOR key&7; coalesced lane=key loads; b128 writes). 3 MFMA
//     (hh,hl,lh) => ~2^-17 error, same budget as verified k_self V-split.
//     Norm: lane-local after shfl_xor(16/32). XT unions with Pl; ssred gone:
//     LDS 53248 -> 3 blocks/CU.
// R8 resubmit: round-8 bench was an infra failure (container acquire died
//     twice, no GPU result). Code re-audited (barriers uniform, OOB clean,
//     frag maps re-derived) and resubmitted unchanged.

typedef __attribute__((ext_vector_type(8))) short short8v;
typedef __attribute__((ext_vector_type(4))) short short4v;
typedef __attribute__((ext_vector_type(4))) float float4v;
typedef __attribute__((ext_vector_type(4))) unsigned int uint4v;

__device__ __forceinline__ float b2f(unsigned short h){
  union { unsigned int u; float f; } c; c.u = ((unsigned int)h) << 16; return c.f;
}
__device__ __forceinline__ unsigned short f2b(float f){
  union { float f; unsigned int u; } c; c.f = f;
  unsigned int u = c.u;
  u += 0x7fffu + ((u >> 16) & 1u);     // round-to-nearest-even
  return (unsigned short)(u >> 16);
}
// flag resolve: fi==-1 forced f32, fi==-2 forced bf16, else flags[fi] (1=f32,0=bf16)
__device__ __forceinline__ int getf(const int* flags, int fi){
  return (fi == -1) ? 1 : ((fi == -2) ? 0 : flags[fi]);
}
__device__ __forceinline__ float ld1(const void* p, long i, int f32f){
  return f32f ? ((const float*)p)[i] : b2f(((const unsigned short*)p)[i]);
}
__device__ __forceinline__ void ld8(const void* p, long i, int f32f, float* o){
  if (f32f){
    float4v a = *(const float4v*)((const float*)p + i);
    float4v b = *(const float4v*)((const float*)p + i + 4);
    o[0]=a[0];o[1]=a[1];o[2]=a[2];o[3]=a[3];o[4]=b[0];o[5]=b[1];o[6]=b[2];o[7]=b[3];
  } else {
    short8v v = *(const short8v*)((const unsigned short*)p + i);
    #pragma unroll
    for (int j=0;j<8;j++) o[j] = b2f((unsigned short)v[j]);
  }
}
__device__ __forceinline__ void ld4(const void* p, long i, int f32f, float* o){
  if (f32f){
    float4v a = *(const float4v*)((const float*)p + i);
    o[0]=a[0];o[1]=a[1];o[2]=a[2];o[3]=a[3];
  } else {
    short4v v = *(const short4v*)((const unsigned short*)p + i);
    #pragma unroll
    for (int j=0;j<4;j++) o[j] = b2f((unsigned short)v[j]);
  }
}

__device__ __forceinline__ float4v mfma16(short8v a, short8v b, float4v c){
  return __builtin_amdgcn_mfma_f32_16x16x32_bf16(a, b, c, 0, 0, 0);
}

// ---------------------------------------------------------------------------
// k_detect: flags[i]=1 if input i is f32 (bf16-exponent>=200 rate > 6.25% over
// first min(n,8192) uint16s; f32-as-bf16 gives ~11%, real bf16 data ~0%).
// ---------------------------------------------------------------------------
__global__ __launch_bounds__(256) void k_detect(
    const void* p0, const void* p1, const void* p2, const void* p3,
    const void* p4, const void* p5, const void* p6,
    int n0, int n1, int n2, int n3, int n4, int n5, int n6,
    int* __restrict__ flags)
{
  const int i = blockIdx.x, t = threadIdx.x;
  const void* ps[7] = {p0,p1,p2,p3,p4,p5,p6};
  int ns[7] = {n0,n1,n2,n3,n4,n5,n6};
  const unsigned short* u = (const unsigned short*)ps[i];
  int n = ns[i]; if (n > 8192) n = 8192;
  int cnt = 0;
  for (int k=t; k<n; k+=256){
    int e = (u[k] >> 7) & 0xFF;
    cnt += (e >= 200) ? 1 : 0;
  }
  __shared__ int red[256];
  red[t] = cnt; __syncthreads();
  for (int off=128; off>0; off>>=1){
    if (t < off) red[t] += red[t+off];
    __syncthreads();
  }
  if (t == 0) flags[i] = (red[0]*16 > n) ? 1 : 0;
}

// ---------------------------------------------------------------------------
// k_proj_g: Out[s][n][128] (bf16) = l2norm(X_token(n) @ W^T + b)
// X layout: [(f*4+s)*512 + ch]*1024 + p, f=n>>10, p=n&1023. Block=128 (d).
// ---------------------------------------------------------------------------
__global__ __launch_bounds__(128) void k_proj_g(
    const void* __restrict__ Xv, int xfi,
    const void* __restrict__ Wv, int wfi,
    const void* __restrict__ Bv, int bfi,
    const int* __restrict__ flags,
    unsigned short* __restrict__ Out, int Ntot)
{
  const int n = blockIdx.x, s = blockIdx.y, d = threadIdx.x;
  const int xf = getf(flags,xfi), wf = getf(flags,wfi), bf = getf(flags,bfi);
  const int f = n >> 10, p = n & 1023;
  const long base = ((long)(f*4 + s) * 512) * 1024 + p;
  float acc = ld1(Bv, d, bf);
  const long wbase = (long)d * 512;
  float wv[8];
  for (int ch=0; ch<512; ch+=8){
    ld8(Wv, wbase + ch, wf, wv);
    #pragma unroll
    for (int j=0;j<8;j++)
      acc += ld1(Xv, base + (long)(ch+j)*1024, xf) * wv[j];
  }
  __shared__ float red[128];
  red[d] = acc*acc;
  __syncthreads();
  for (int off=64; off>0; off>>=1){
    if (d < off) red[d] += red[d+off];
    __syncthreads();
  }
  float r = 1.f / fmaxf(sqrtf(fmaxf(red[0], 0.f)), 1e-12f);
  Out[((long)s*Ntot + n)*128 + d] = f2b(acc * r);
}

// ---------------------------------------------------------------------------
// k_self (R7, MFMA, verified): block = (q-tile 16, s), 4 waves x 128 ch.
// ---------------------------------------------------------------------------
__global__ __launch_bounds__(256) void k_self(
    const unsigned short* __restrict__ wq,   // [s][1024][128] bf16 (ws)
    const void* __restrict__ tgt,            // [s][512][1024] flagged
    const int* __restrict__ flags,
    unsigned short* __restrict__ Y)          // [s][512][1024] bf16
{
  const int n0 = blockIdx.x * 16, s = blockIdx.y, t = threadIdx.x;
  const int tf = flags[0];
  const int l = t & 63, w = t >> 6;
  const int lr = l & 15, lg = l >> 4;

  __shared__ unsigned short Pl[16*128];    // 4 KB [q][kk] bf16, row-swizzled
  __shared__ float zl[4*16];               // [wave][q]

  short8v qf[4];
  {
    const unsigned short* qbase = wq + ((long)s*1024 + n0 + lr)*128;
    #pragma unroll
    for (int kb=0; kb<4; kb++)
      qf[kb] = *(const short8v*)(qbase + kb*32 + lg*8);
  }

  float4v Ofr[8];
  #pragma unroll
  for (int ct=0; ct<8; ct++) Ofr[ct] = (float4v){0.f,0.f,0.f,0.f};
  float zacc[4] = {0.f,0.f,0.f,0.f};

  #pragma unroll 1
  for (int kc=0; kc<8; ++kc){
    #pragma unroll
    for (int kss=0; kss<2; kss++){
      const int kk0 = (w*2 + kss)*16;
      const unsigned short* kb_ = wq + ((long)s*1024 + kc*128 + kk0 + lr)*128;
      float4v sacc = {0.f,0.f,0.f,0.f};
      #pragma unroll
      for (int kb=0; kb<4; kb++){
        short8v kf = *(const short8v*)(kb_ + kb*32 + lg*8);
        sacc = mfma16(qf[kb], kf, sacc);
      }
      #pragma unroll
      for (int r=0; r<4; r++){
        float p = __expf(30.f*sacc[r] - 30.f);
        unsigned short pb = f2b(p);
        zacc[r] += b2f(pb);
        const int q = lg*4 + r;
        const int kk = kk0 + lr;
        *(unsigned short*)((char*)Pl + q*256 + (((kk*2)) ^ ((q&7)<<4))) = pb;
      }
    }
    __syncthreads();
    short8v pfr[4];
    #pragma unroll
    for (int kt=0; kt<4; kt++){
      const int k0 = kt*32 + lg*8;
      pfr[kt] = *(const short8v*)((char*)Pl + lr*256 + ((k0*2) ^ ((lr&7)<<4)));
    }
    if (tf){
      #pragma unroll
      for (int ct=0; ct<8; ct++){
        const int ch = w*128 + ct*16 + lr;
        const float* vb = (const float*)tgt + ((long)s*512 + ch)*1024 + kc*128;
        #pragma unroll
        for (int kt=0; kt<4; kt++){
          float4v a = *(const float4v*)(vb + kt*32 + lg*8);
          float4v b = *(const float4v*)(vb + kt*32 + lg*8 + 4);
          float v8[8] = {a[0],a[1],a[2],a[3],b[0],b[1],b[2],b[3]};
          short8v vh, vl;
          #pragma unroll
          for (int j=0;j<8;j++){
            unsigned short h = f2b(v8[j]);
            vh[j] = (short)h;
            vl[j] = (short)f2b(v8[j] - b2f(h));
          }
          Ofr[ct] = mfma16(pfr[kt], vh, Ofr[ct]);
          Ofr[ct] = mfma16(pfr[kt], vl, Ofr[ct]);
        }
      }
    } else {
      #pragma unroll
      for (int ct=0; ct<8; ct++){
        const int ch = w*128 + ct*16 + lr;
        const unsigned short* vb = (const unsigned short*)tgt
                                   + ((long)s*512 + ch)*1024 + kc*128;
        #pragma unroll
        for (int kt=0; kt<4; kt++){
          short8v vv = *(const short8v*)(vb + kt*32 + lg*8);
          Ofr[ct] = mfma16(pfr[kt], vv, Ofr[ct]);
        }
      }
    }
    __syncthreads();
  }

  #pragma unroll
  for (int r=0; r<4; r++){
    float z = zacc[r];
    z += __shfl_xor(z, 1);
    z += __shfl_xor(z, 2);
    z += __shfl_xor(z, 4);
    z += __shfl_xor(z, 8);
    zacc[r] = z;
  }
  if (lr == 0){
    #pragma unroll
    for (int r=0; r<4; r++) zl[w*16 + lg*4 + r] = zacc[r];
  }
  __syncthreads();
  float izq[4];
  #pragma unroll
  for (int r=0; r<4; r++){
    const int q = lg*4 + r;
    float z = zl[q] + zl[16+q] + zl[32+q] + zl[48+q];
    izq[r] = 1.f / fmaxf(z, 1e-30f);
  }
  #pragma unroll
  for (int ct=0; ct<8; ct++){
    const int ch = w*128 + ct*16 + lr;
    const long base = ((long)s*512 + ch)*1024 + n0 + lg*4;
    float tv[4];
    ld4(tgt, base, tf, tv);
    short4v ob;
    #pragma unroll
    for (int r=0; r<4; r++)
      ob[r] = (short)f2b(tv[r] + Ofr[ct][r]*izq[r]);
    *(short4v*)(Y + base) = ob;
  }
}

// ---------------------------------------------------------------------------
// k_inorm: in-place InstanceNorm (biased var, eps 1e-5) over 1024 tokens.
// ---------------------------------------------------------------------------
__global__ __launch_bounds__(256) void k_inorm(unsigned short* __restrict__ Y)
{
  const int ch = blockIdx.x, s = blockIdx.y, t = threadIdx.x;
  unsigned short* row = Y + ((long)s*512 + ch)*1024;
  float v[4]; float sum=0.f, ss=0.f;
  #pragma unroll
  for (int i=0;i<4;i++){ v[i]=b2f(row[t+256*i]); sum+=v[i]; ss+=v[i]*v[i]; }
  __shared__ float r1[256], r2[256];
  r1[t]=sum; r2[t]=ss; __syncthreads();
  for (int off=128; off>0; off>>=1){
    if (t<off){ r1[t]+=r1[t+off]; r2[t]+=r2[t+off]; }
    __syncthreads();
  }
  float mean = r1[0]*(1.f/1024.f);
  float var  = fmaxf(r2[0]*(1.f/1024.f) - mean*mean, 0.f);
  float rstd = rsqrtf(var + 1e-5f);
  #pragma unroll
  for (int i=0;i<4;i++) row[t+256*i] = f2b((v[i]-mean)*rstd);
}

// ---------------------------------------------------------------------------
// k_crossfuse (R8): block = (key-chunk c, s), 256 threads (4 waves).
// Chunk = 128 keys of frame f=c>>3 at p0=(c&7)*128. Partial-group grp=c&7.
//
// Phase A (MFMA): D[dim][key] = W(A) x X^T(B), ch in 16 chunks of 32.
//   XT tile (=Pl union): [key][plane hi/lo][ch32] bf16, 128B rows, 16B-granule
//   XOR (key&7). Staged per chunk: thread t -> key=t&127, ch-half=(t>>7)*16:
//   16 coalesced scalar loads -> hi/lo cvt -> 4 b128 writes.
//   Wave w owns key-subtiles {2w, 2w+1}: B hi/lo frags from XT; per dim-
//   subtile ds: A = W[ds*16+lr][chunk+lg*8..+7] hi/lo from global (L1-bcast);
//   3 mfma (AhBh, AhBl, AlBh) into acc[kss][ds] (statically indexed!).
//   Epilogue: +bias, ss = sum acc^2 lane-local -> shfl_xor(16,32) -> full
//   128-dim norm per key (col=lr is wave-local) -> bf16 scatter into Kl
//   (same swizzled layout phase B reads).
// Phase A2: PE tile bf16 [e][k] swizzled (unchanged).
// Phase B (MFMA, frozen R5-R7): per q-tile: Q A-frags global; 8 key-sub x
//   4 mfma -> S; exp; P -> swizzled Pl; 4 mfma P x PE -> O; Z butterfly;
//   atomicAdd into group partials.
// LDS: Kl 32K + PEb 4K + Pl/XT 16K = 53248 B -> 3 blocks/CU.
// ---------------------------------------------------------------------------
__global__ __launch_bounds__(256) void k_crossfuse(
    const unsigned short* __restrict__ wqC,  // [s][1024][128] bf16 (ws)
    const void* __restrict__ mem,            // [(f*4+s)*512+ch][1024] flagged
    const void* __restrict__ pe,             // [(f*4+s)*16+e][1024] flagged
    const void* __restrict__ Wv,             // [128][512] flagged
    const void* __restrict__ Bv,             // [128] flagged
    const int* __restrict__ flags,
    float* __restrict__ OZp)                 // [8 grp][4 s][1024][17] f32, zeroed
{
  const int c = blockIdx.x, s = blockIdx.y, t = threadIdx.x;
  const int f = c >> 3, p0 = (c & 7) * 128, grp = c & 7;
  const int mf = flags[1], pf = flags[2], wf = flags[5], bf = flags[6];

  __shared__ unsigned short Kl[128*128];   // 32 KB [key][d] bf16 XOR-swizzled
  __shared__ unsigned short PEb[16*128];   //  4 KB [e][k]  bf16 XOR-swizzled
  __shared__ unsigned short Pl[4*16*128];  // 16 KB; phase A: XT staging tile

  const int l = t & 63, w = t >> 6;
  const int lr = l & 15, lg = l >> 4;

  // ---- Phase A2 first: pos_enc tile bf16 [e][k] swizzled (independent)
  {
    const int e = t >> 4, k0 = (t & 15) * 8;
    float pv8[8];
    ld8(pe, ((long)((f*4 + s)*16 + e))*1024 + p0 + k0, pf, pv8);
    uint4v v;
    #pragma unroll
    for (int wd=0; wd<4; wd++){
      unsigned int lo = f2b(pv8[2*wd]);
      unsigned int hi = f2b(pv8[2*wd+1]);
      v[wd] = lo | (hi << 16);
    }
    *(uint4v*)((char*)PEb + e*256 + (((k0*2)) ^ ((e & 7) << 4))) = v;
  }

  // ---- Phase A: MFMA projection of this block's 128 keys
  {
    char* XT = (char*)Pl;                  // [key][plane][ch32], 128B rows
    float4v acc[2][8];
    #pragma unroll
    for (int i=0;i<2;i++)
      #pragma unroll
      for (int j=0;j<8;j++) acc[i][j] = (float4v){0.f,0.f,0.f,0.f};

    const int key_st = t & 127;            // staging role
    const int chh = (t >> 7) * 16;
    const int kx_st = key_st & 7;
    const long xrow0 = ((long)(f*4 + s) * 512) * 1024 + p0 + key_st;
    char* strow = XT + key_st*128;

    for (int chunk=0; chunk<512; chunk+=32){
      // stage XT: 16 coalesced scalar loads (lane=key), hi/lo cvt, 4 b128
      {
        unsigned int hp[8], lp[8];
        #pragma unroll
        for (int cc=0; cc<16; cc+=2){
          float x0 = ld1(mem, xrow0 + (long)(chunk+chh+cc  )*1024, mf);
          float x1 = ld1(mem, xrow0 + (long)(chunk+chh+cc+1)*1024, mf);
          unsigned short h0 = f2b(x0), h1 = f2b(x1);
          unsigned short l0 = f2b(x0 - b2f(h0)), l1 = f2b(x1 - b2f(h1));
          hp[cc>>1] = (unsigned)h0 | ((unsigned)h1<<16);
          lp[cc>>1] = (unsigned)l0 | ((unsigned)l1<<16);
        }
        const int g0 = chh >> 3;           // 0 or 2
        uint4v vh0 = {hp[0],hp[1],hp[2],hp[3]};
        uint4v vh1 = {hp[4],hp[5],hp[6],hp[7]};
        uint4v vl0 = {lp[0],lp[1],lp[2],lp[3]};
        uint4v vl1 = {lp[4],lp[5],lp[6],lp[7]};
        *(uint4v*)(strow + (((g0  ) ^ kx_st) << 4)) = vh0;
        *(uint4v*)(strow + (((g0+1) ^ kx_st) << 4)) = vh1;
        *(uint4v*)(strow + (((g0+4) ^ kx_st) << 4)) = vl0;
        *(uint4v*)(strow + (((g0+5) ^ kx_st) << 4)) = vl1;
      }
      __syncthreads();
      // B-frags for this wave's 2 key-subtiles
      short8v Bh[2], Bl[2];
      #pragma unroll
      for (int kss=0; kss<2; kss++){
        const int key = (w*2 + kss)*16 + lr;
        const char* row = XT + key*128;
        const int kx = key & 7;
        Bh[kss] = *(const short8v*)(row + (((lg    ) ^ kx) << 4));
        Bl[kss] = *(const short8v*)(row + (((lg + 4) ^ kx) << 4));
      }
      // A-frags per dim-subtile from W (global, wave-broadcast), 3 mfma each
      #pragma unroll
      for (int ds=0; ds<8; ds++){
        float wv8[8];
        ld8(Wv, (long)(ds*16 + lr)*512 + chunk + lg*8, wf, wv8);
        short8v Ah, Al;
        #pragma unroll
        for (int j=0;j<8;j++){
          unsigned short h = f2b(wv8[j]);
          Ah[j] = (short)h;
          Al[j] = (short)f2b(wv8[j] - b2f(h));
        }
        acc[0][ds] = mfma16(Ah, Bh[0], acc[0][ds]);
        acc[0][ds] = mfma16(Ah, Bl[0], acc[0][ds]);
        acc[0][ds] = mfma16(Al, Bh[0], acc[0][ds]);
        acc[1][ds] = mfma16(Ah, Bh[1], acc[1][ds]);
        acc[1][ds] = mfma16(Ah, Bl[1], acc[1][ds]);
        acc[1][ds] = mfma16(Al, Bh[1], acc[1][ds]);
      }
      __syncthreads();
    }
    // epilogue: bias, l2norm (lane-local after shfl), scatter to Kl
    float bias[8][4];
    #pragma unroll
    for (int ds=0; ds<8; ds++)
      #pragma unroll
      for (int r=0; r<4; r++)
        bias[ds][r] = ld1(Bv, ds*16 + lg*4 + r, bf);
    #pragma unroll
    for (int kss=0; kss<2; kss++){
      float ss = 0.f;
      #pragma unroll
      for (int ds=0; ds<8; ds++){
        #pragma unroll
        for (int r=0; r<4; r++){
          float v = acc[kss][ds][r] + bias[ds][r];
          acc[kss][ds][r] = v;
          ss += v*v;
        }
      }
      ss += __shfl_xor(ss, 16);
      ss += __shfl_xor(ss, 32);
      float inv = 1.f / fmaxf(sqrtf(fmaxf(ss, 0.f)), 1e-12f);
      const int key = (w*2 + kss)*16 + lr;
      char* krow = (char*)Kl + key*256;
      const int kx = key & 7;
      #pragma unroll
      for (int ds=0; ds<8; ds++){
        #pragma unroll
        for (int r=0; r<4; r++){
          const int dim = ds*16 + lg*4 + r;
          *(unsigned short*)(krow + (((dim>>3) ^ kx) << 4) + (dim & 7)*2)
              = f2b(acc[kss][ds][r] * inv);
        }
      }
    }
  }
  __syncthreads();

  // ---- Phase B: MFMA, waves independent (frozen from R5/R6/R7)
  char* PlW = (char*)Pl + w*4096;          // per-wave P tile

  short8v peb[4];
  #pragma unroll
  for (int kb=0; kb<4; kb++){
    const int k0 = kb*32 + lg*8;
    peb[kb] = *(const short8v*)((char*)PEb + lr*256 + ((k0*2) ^ ((lr & 7) << 4)));
  }

  for (int qt = w; qt < 64; qt += 4){
    short8v qf[4];
    const unsigned short* qbase = wqC + ((long)s*1024 + qt*16 + lr)*128;
    #pragma unroll
    for (int kb=0; kb<4; kb++)
      qf[kb] = *(const short8v*)(qbase + kb*32 + lg*8);

    float zacc[4] = {0.f, 0.f, 0.f, 0.f};
    #pragma unroll 1
    for (int kt=0; kt<8; ++kt){
      float4v sacc = {0.f, 0.f, 0.f, 0.f};
      const int key = kt*16 + lr;
      const char* krow = (const char*)Kl + key*256;
      const int xk = (key & 7) << 4;
      #pragma unroll
      for (int kb=0; kb<4; kb++){
        short8v kf = *(const short8v*)(krow + (((kb*32 + lg*8)*2) ^ xk));
        sacc = mfma16(qf[kb], kf, sacc);
      }
      #pragma unroll
      for (int r=0; r<4; r++){
        float p = __expf(30.f*sacc[r] - 30.f);
        zacc[r] += p;
        const int q = lg*4 + r;
        *(unsigned short*)(PlW + q*256 + (((kt*16 + lr)*2) ^ ((q & 7) << 4))) = f2b(p);
      }
    }
    float4v pv = {0.f, 0.f, 0.f, 0.f};
    #pragma unroll
    for (int kb=0; kb<4; kb++){
      const int k0 = kb*32 + lg*8;
      short8v pf8 = *(const short8v*)(PlW + lr*256 + ((k0*2) ^ ((lr & 7) << 4)));
      pv = mfma16(pf8, peb[kb], pv);
    }
    #pragma unroll
    for (int r=0; r<4; r++){
      float z = zacc[r];
      z += __shfl_xor(z, 1);
      z += __shfl_xor(z, 2);
      z += __shfl_xor(z, 4);
      z += __shfl_xor(z, 8);
      zacc[r] = z;
    }
    float* oz = OZp + ((((long)grp*4 + s)*1024) + qt*16)*17;
    #pragma unroll
    for (int r=0; r<4; r++)
      atomicAdd(&oz[(lg*4 + r)*17 + lr], pv[r]);
    if (lr == 0){
      #pragma unroll
      for (int r=0; r<4; r++)
        atomicAdd(&oz[(lg*4 + r)*17 + 16], zacc[r]);
    }
  }
}

// ---------------------------------------------------------------------------
// k_final: out (FLOAT32) = sigmoid(O/Z) summing 8 group partials; diagnostic
// if ws too small. out[i], i = ((s*16+e)<<10)+n.
// ---------------------------------------------------------------------------
__global__ __launch_bounds__(256) void k_final(
    const float* __restrict__ OZp, float* __restrict__ out,
    const int* __restrict__ flags, int sane, int detect_ok, int ws_mb)
{
  const int i = blockIdx.x*256 + threadIdx.x;   // 0..65535
  if (!sane){
    float v = 0.5f;
    if (i == 0){
      int F = 0;
      if (detect_ok)
        F = flags[0]*16 + flags[1]*8 + flags[2]*4 + flags[3]*2 + flags[5];
      int wm = ws_mb > 99 ? 99 : ws_mb;
      v = ldexpf(1.f + (float)wm*(1.f/128.f), 40 + F);
    }
    out[i] = v;
    return;
  }
  const int s = i >> 14, e = (i >> 10) & 15, n = i & 1023;
  float x = 0.f, z = 0.f;
  #pragma unroll
  for (int g=0; g<8; g++){
    const float* oz = OZp + (((long)g*4 + s)*1024 + n)*17;
    x += oz[e];
    z += oz[16];
  }
  float r = x / fmaxf(z, 1e-30f);
  out[i] = 1.f / (1.f + __expf(-r));
}

// ---------------------------------------------------------------------------
extern "C" void kernel_launch(void* const* d_in, const int* in_sizes, int n_in,
                              void* d_out, int out_size, void* d_ws, size_t ws_size,
                              hipStream_t stream)
{
  const void* tgt = d_in[0];
  const void* mem = d_in[1];
  const void* pe  = d_in[2];
  const void* wks = d_in[3];
  const void* bks = d_in[4];
  const void* wkc = d_in[5];
  const void* bkc = d_in[6];
  float* out = (float*)d_out;   // [4][16][1024] FLOAT32 (reference output dtype)

  char* w = (char*)d_ws;
  int*            flags = (int*)w;          w += 256;
  unsigned short* wqS = (unsigned short*)w; w += (size_t)4*1024*128*2;   // 1 MB
  unsigned short* wqC = (unsigned short*)w; w += (size_t)4*1024*128*2;   // 1 MB
  unsigned short* Y   = (unsigned short*)w; w += (size_t)4*512*1024*2;   // 4 MB
  float*          OZ  = (float*)w;          w += (size_t)4*1024*17*4;    // 272 KB
  const size_t NEED = (size_t)(w - (char*)d_ws);

  // OZ partials (8 groups) live in the dead Y buffer during k_crossfuse.
  float* OZp = (float*)Y;                   // 8*4*1024*17*4 = 2228224 B <= 4 MB

  const int detect_ok = ws_size >= 4096;
  const int sane = ws_size >= NEED;

  if (detect_ok)
    hipLaunchKernelGGL(k_detect, dim3(7), dim3(256), 0, stream,
                       tgt, mem, pe, wks, bks, wkc, bkc,
                       in_sizes[0], in_sizes[1], in_sizes[2], in_sizes[3],
                       in_sizes[4], in_sizes[5], in_sizes[6], flags);
  if (sane){
    hipLaunchKernelGGL(k_proj_g, dim3(1024,4), dim3(128), 0, stream,
                       tgt, 0, wks, 3, bks, 4, flags, wqS, 1024);
    hipLaunchKernelGGL(k_self, dim3(64,4), dim3(256), 0, stream,
                       wqS, tgt, flags, Y);
    hipLaunchKernelGGL(k_inorm, dim3(512,4), dim3(256), 0, stream, Y);
    hipLaunchKernelGGL(k_proj_g, dim3(1024,4), dim3(128), 0, stream,
                       (const void*)Y, -2, wkc, 5, bkc, 6, flags, wqC, 1024);
    // Y is dead from here: reuse as OZ partial buffer.
    hipMemsetAsync(OZp, 0, (size_t)8*4*1024*17*4, stream);
    hipLaunchKernelGGL(k_crossfuse, dim3(128,4), dim3(256), 0, stream,
                       wqC, mem, pe, wkc, bkc, flags, OZp);
  }
  hipLaunchKernelGGL(k_final, dim3(256), dim3(256), 0, stream,
                     (const float*)OZp, out, flags, sane, detect_ok,
                     (int)(ws_size >> 20));
}